// Round 3
// baseline (444.666 us; speedup 1.0000x reference)
//
#include <hip/hip_runtime.h>

// CatGWRegression on MI355X — fused GAT + GATW + regression head.
// Pipeline:
//  k1_proj : p = x@Wp1 (bf16, stored transposed p_T[c][j]), skipb = x@Wskip1+bias1,
//            s_src/s_tgt row scores (fused epilogue reductions)
//  k3_attn : flash-style masked softmax attention, e-weights computed directly in
//            MFMA A-frag layout, B-frags loaded from global p_T. No LDS/barriers.
//            Epilogue: normalize, +skip, elu -> overwrites skipb (out_elu).
//  k4a     : va = Wp2@a_src2, vb = Wp2@a_tgt2 (p2 eliminated by associativity)
//  k4b     : ss = out_elu@va, st = out_elu@vb
//  k56     : FUSED k5+k6 (fp32, no new layouts): during the LDS staging step,
//            msw = relu(ss_i+st_j)*sw is COMPUTED (k5's exact formula) instead of
//            re-read, written once to d_out (output 2), staged in LDS, and
//            GEMM-accumulated vs W1 (k6's exact loop, tile widened 16->32 rows).
//            Removes k5's 64MB write + k6's 64MB re-read; doubles FMA density.
//  k7_head : beta = lrelu((tmp1+b1)@W2+b2)@W3+b3)*ols, y_hat = sum(beta*vx)
//
// NOTE: an MFMA-based k56 (bf16 W1^T) failed correctness with junk in a few msw
// elements (absmax 468) that inspection could not localize; reverted to the
// verified fp32 structure. Do not re-attempt without an isolation test.

#define NN 4096
#define FF 128
#define DD2 256
#define NH1 96

typedef __attribute__((ext_vector_type(8))) short bf16x8;
typedef __attribute__((ext_vector_type(4))) float f32x4;

__device__ __forceinline__ short f2bf(float f) {
  unsigned u = __float_as_uint(f);
  u = u + 0x7FFFu + ((u >> 16) & 1u);   // RNE
  return (short)(u >> 16);
}

// ---------------------------------------------------------------- k1
// grid 256, block 256. Block handles 16 rows x all 256 cols; K=128 streamed.
// Weights read from global (L2-hot across blocks), x tile staged in LDS.
__global__ __launch_bounds__(256) void k1_proj(
    const float* __restrict__ x, const float* __restrict__ Wp1,
    const float* __restrict__ Wsk, const float* __restrict__ bias1,
    const float* __restrict__ as1, const float* __restrict__ at1,
    short* __restrict__ pT, float* __restrict__ skipb,
    float* __restrict__ s_src, float* __restrict__ s_tgt)
{
  __shared__ float xs[16][FF];
  const int t = threadIdx.x;
  const int r0 = blockIdx.x * 16;
  for (int i = t; i < 16 * FF; i += 256)
    xs[i >> 7][i & 127] = x[(size_t)r0 * FF + i];
  __syncthreads();

  const int c = t;
  float accp[16], accs[16];
#pragma unroll
  for (int i = 0; i < 16; ++i) { accp[i] = 0.f; accs[i] = 0.f; }

  for (int k = 0; k < FF; k += 4) {
    float wp[4], wk[4];
#pragma unroll
    for (int u = 0; u < 4; ++u) {
      wp[u] = Wp1[(size_t)(k + u) * DD2 + c];
      wk[u] = Wsk[(size_t)(k + u) * DD2 + c];
    }
#pragma unroll
    for (int rr = 0; rr < 16; ++rr) {
      const float4 xv = *(const float4*)&xs[rr][k];  // uniform addr -> LDS broadcast
      accp[rr] += xv.x * wp[0] + xv.y * wp[1] + xv.z * wp[2] + xv.w * wp[3];
      accs[rr] += xv.x * wk[0] + xv.y * wk[1] + xv.z * wk[2] + xv.w * wk[3];
    }
  }

  const float asv = as1[t], atv = at1[t];  // a_src1[h][f], t = h*64+f
  const float bv = bias1[c];
  const int h = t >> 6;
  const int lane = t & 63;

#pragma unroll
  for (int rr = 0; rr < 16; ++rr)
    skipb[(size_t)(r0 + rr) * DD2 + c] = accs[rr] + bv;

  {  // p_T bf16, packed pair stores (column of p = row of p_T, contiguous in j)
    unsigned* dst = (unsigned*)(pT + (size_t)c * NN + r0);
#pragma unroll
    for (int rr = 0; rr < 16; rr += 2) {
      unsigned lo = (unsigned short)f2bf(accp[rr]);
      unsigned hi = (unsigned short)f2bf(accp[rr + 1]);
      dst[rr >> 1] = lo | (hi << 16);
    }
  }

#pragma unroll
  for (int rr = 0; rr < 16; ++rr) {  // s_src[h][i], s_tgt[h][i]
    float ps = accp[rr] * asv, pt = accp[rr] * atv;
#pragma unroll
    for (int off = 32; off > 0; off >>= 1) {
      ps += __shfl_down(ps, off);
      pt += __shfl_down(pt, off);
    }
    if (lane == 0) { s_src[h * NN + r0 + rr] = ps; s_tgt[h * NN + r0 + rr] = pt; }
  }
}

// ---------------------------------------------------------------- k3
// grid 256, block 256 (wave = head). 16 target rows per block.
// Single pass over j: e = mask ? exp(lrelu(s_src+s_tgt)) : 0, computed per-lane
// directly in A-frag layout (m=lane&15 row, k=(lane>>4)*8+u); B-frags (p_T bf16)
// loaded from global. Unnormalized accumulate + l-sum, normalize at end.
__global__ __launch_bounds__(256) void k3_attn(
    const short* __restrict__ pT, const float* __restrict__ s_src,
    const float* __restrict__ s_tgt, const float* __restrict__ sw,
    float* __restrict__ io /* in: skip+bias, out: elu(out) */)
{
  const int t = threadIdx.x;
  const int lane = t & 63;
  const int h = t >> 6;
  const int m = lane & 15;
  const int q = lane >> 4;
  const int i0 = blockIdx.x * 16;

  const float ssrc = s_src[h * NN + i0 + m];
  const float* stg = s_tgt + h * NN;
  const float* swrow = sw + (size_t)(i0 + m) * NN;
  const short* pbase = pT + (size_t)(h * 64 + m) * NN;

  f32x4 acc0 = {0.f, 0.f, 0.f, 0.f};
  f32x4 acc1 = acc0, acc2 = acc0, acc3 = acc0;
  float lsum = 0.f;

  for (int jt = 0; jt < NN; jt += 32) {
    const int jb = jt + q * 8;
    const float4 t0 = *(const float4*)(stg + jb);
    const float4 t1 = *(const float4*)(stg + jb + 4);
    const float4 w0 = *(const float4*)(swrow + jb);
    const float4 w1 = *(const float4*)(swrow + jb + 4);
    const float tj[8] = {t0.x, t0.y, t0.z, t0.w, t1.x, t1.y, t1.z, t1.w};
    const float wv[8] = {w0.x, w0.y, w0.z, w0.w, w1.x, w1.y, w1.z, w1.w};
    bf16x8 af;
    float esum = 0.f;
#pragma unroll
    for (int u = 0; u < 8; ++u) {
      float s = ssrc + tj[u];
      s = fmaxf(s, 0.2f * s);              // leaky_relu(0.2)
      float e = __expf(s);
      e = (wv[u] > 0.f) ? e : 0.f;         // mask: spatial_weights > 0
      esum += e;
      af[u] = f2bf(e);
    }
    lsum += esum;
    const bf16x8 b0 = *(const bf16x8*)(pbase + jb);
    const bf16x8 b1 = *(const bf16x8*)(pbase + 16 * NN + jb);
    const bf16x8 b2 = *(const bf16x8*)(pbase + 32 * NN + jb);
    const bf16x8 b3 = *(const bf16x8*)(pbase + 48 * NN + jb);
    acc0 = __builtin_amdgcn_mfma_f32_16x16x32_bf16(af, b0, acc0, 0, 0, 0);
    acc1 = __builtin_amdgcn_mfma_f32_16x16x32_bf16(af, b1, acc1, 0, 0, 0);
    acc2 = __builtin_amdgcn_mfma_f32_16x16x32_bf16(af, b2, acc2, 0, 0, 0);
    acc3 = __builtin_amdgcn_mfma_f32_16x16x32_bf16(af, b3, acc3, 0, 0, 0);
  }

  // l per row: reduce the 4 quads, then fetch l for C-frag rows (q*4+g)
  lsum += __shfl_xor(lsum, 16);
  lsum += __shfl_xor(lsum, 32);
  float linv[4];
#pragma unroll
  for (int g = 0; g < 4; ++g) linv[g] = 1.0f / __shfl(lsum, q * 4 + g);

  const f32x4 accs[4] = {acc0, acc1, acc2, acc3};
#pragma unroll
  for (int sub = 0; sub < 4; ++sub) {
    const int cg = h * 64 + sub * 16 + m;  // C col = lane&15
#pragma unroll
    for (int g = 0; g < 4; ++g) {
      const int r = i0 + q * 4 + g;        // C row = quad*4+reg
      float z = accs[sub][g] * linv[g] + io[(size_t)r * DD2 + cg];
      z = (z > 0.f) ? z : (__expf(z) - 1.f);   // elu
      io[(size_t)r * DD2 + cg] = z;
    }
  }
}

// ---------------------------------------------------------------- k4a
// va = Wp2 @ a_src2, vb = Wp2 @ a_tgt2. grid 64, block 256 (wave per row).
__global__ __launch_bounds__(256) void k4a_vab(
    const float* __restrict__ Wp2, const float* __restrict__ as2,
    const float* __restrict__ at2, float* __restrict__ va, float* __restrict__ vb)
{
  const int lane = threadIdx.x & 63;
  const int w = threadIdx.x >> 6;
  const int r = blockIdx.x * 4 + w;
  const float4 wv = *(const float4*)(Wp2 + (size_t)r * DD2 + lane * 4);
  const float4 a = *(const float4*)(as2 + lane * 4);
  const float4 b = *(const float4*)(at2 + lane * 4);
  float ps = wv.x * a.x + wv.y * a.y + wv.z * a.z + wv.w * a.w;
  float pt = wv.x * b.x + wv.y * b.y + wv.z * b.z + wv.w * b.w;
#pragma unroll
  for (int off = 32; off > 0; off >>= 1) {
    ps += __shfl_down(ps, off);
    pt += __shfl_down(pt, off);
  }
  if (lane == 0) { va[r] = ps; vb[r] = pt; }
}

// ---------------------------------------------------------------- k4b
// ss[n] = out_elu[n]·va, st[n] = out_elu[n]·vb. grid 1024, wave per row.
__global__ __launch_bounds__(256) void k4b_sst(
    const float* __restrict__ oe, const float* __restrict__ va,
    const float* __restrict__ vb, float* __restrict__ ss, float* __restrict__ st)
{
  const int lane = threadIdx.x & 63;
  const int w = threadIdx.x >> 6;
  const int r = blockIdx.x * 4 + w;
  const float4 ov = *(const float4*)(oe + (size_t)r * DD2 + lane * 4);
  const float4 a = *(const float4*)(va + lane * 4);
  const float4 b = *(const float4*)(vb + lane * 4);
  float ps = ov.x * a.x + ov.y * a.y + ov.z * a.z + ov.w * a.w;
  float pt = ov.x * b.x + ov.y * b.y + ov.z * b.z + ov.w * b.w;
#pragma unroll
  for (int off = 32; off > 0; off >>= 1) {
    ps += __shfl_down(ps, off);
    pt += __shfl_down(pt, off);
  }
  if (lane == 0) { ss[r] = ps; st[r] = pt; }
}

// ---------------------------------------------------------------- k56
// FUSED k5+k6 (pure fp32): tmp1 = msw @ W1 with msw computed on the fly.
// M=4096 N=96 K=4096, k-split 8 + atomicAdd (round-0-verified pattern).
// grid 1024 = 128 row-stripes(32 rows) x 8 k-splits. block 192: c = t%96,
// half = t/96 (16 rows each of the 32-row tile), acc[16].
// Staging step computes v = relu(ss_i+st_j)*sw (k5's exact formula), writes it
// once to msw (d_out, output 2; (stripe,ksplit) blocks cover disjoint (i,j)),
// and stages it in LDS for the GEMM.
__global__ __launch_bounds__(192) void k56_fused(
    const float* __restrict__ ss, const float* __restrict__ stv,
    const float* __restrict__ sw, const float* __restrict__ W1g,
    float* __restrict__ msw, float* __restrict__ tmp1)
{
  __shared__ float ms[32][64];
  const int t = threadIdx.x;
  const int rb = blockIdx.x >> 3;
  const int kb = blockIdx.x & 7;
  const int r0 = rb * 32;
  const int k0 = kb * 512;
  const int c = t % 96;
  const int half = t / 96;
  float acc[16];
#pragma unroll
  for (int i = 0; i < 16; ++i) acc[i] = 0.f;

  for (int kt = k0; kt < k0 + 512; kt += 64) {
    __syncthreads();
    for (int i = t; i < 32 * 64; i += 192) {
      const int rr = i >> 6, kk = i & 63;
      const int row = r0 + rr, j = kt + kk;
      const float v = fmaxf(ss[row] + stv[j], 0.f) * sw[(size_t)row * NN + j];
      ms[rr][kk] = v;
      msw[(size_t)row * NN + j] = v;
    }
    __syncthreads();
    for (int kk = 0; kk < 64; kk += 4) {
      const float b0 = W1g[(size_t)(kt + kk) * NH1 + c];
      const float b1 = W1g[(size_t)(kt + kk + 1) * NH1 + c];
      const float b2 = W1g[(size_t)(kt + kk + 2) * NH1 + c];
      const float b3 = W1g[(size_t)(kt + kk + 3) * NH1 + c];
#pragma unroll
      for (int rr = 0; rr < 16; ++rr) {
        const float4 av = *(const float4*)&ms[half * 16 + rr][kk];  // broadcast
        acc[rr] += av.x * b0 + av.y * b1 + av.z * b2 + av.w * b3;
      }
    }
  }
#pragma unroll
  for (int rr = 0; rr < 16; ++rr)
    atomicAdd(&tmp1[(size_t)(r0 + half * 16 + rr) * NH1 + c], acc[rr]);
}

// ---------------------------------------------------------------- k7
// beta/y_hat head. grid 512 (8 rows/block), block 256.
__global__ __launch_bounds__(256) void k7_head(
    const float* __restrict__ tmp1, const float* __restrict__ b1,
    const float* __restrict__ W2, const float* __restrict__ b2,
    const float* __restrict__ W3, const float* __restrict__ b3,
    const float* __restrict__ ols, const float* __restrict__ vx,
    float* __restrict__ beta, float* __restrict__ yhat)
{
  __shared__ float w2s[96][32];
  __shared__ float w3s[32][16];
  __shared__ float t1s[8][96];
  __shared__ float t2s[8][33];
  const int t = threadIdx.x;
  const int r0 = blockIdx.x * 8;
  for (int i = t; i < 96 * 32; i += 256) w2s[i >> 5][i & 31] = W2[i];
  for (int i = t; i < 32 * 16; i += 256) w3s[i >> 4][i & 15] = W3[i];
  for (int i = t; i < 8 * 96; i += 256) {
    const int rr = i / 96, k = i - rr * 96;
    t1s[rr][k] = tmp1[(size_t)(r0 + rr) * 96 + k] + b1[k];
  }
  __syncthreads();
  {
    const int rr = t >> 5, c2 = t & 31;
    float a = b2[c2];
    for (int k = 0; k < 96; ++k) a += t1s[rr][k] * w2s[k][c2];
    t2s[rr][c2] = a;
  }
  __syncthreads();
  const int rr = t >> 5;
  const int v = t & 31;
  if (v < 16) {
    float z = b3[v];
#pragma unroll
    for (int k = 0; k < 32; ++k) z += t2s[rr][k] * w3s[k][v];
    z = fmaxf(z, 0.2f * z);               // leaky_relu(0.2)
    const float bvv = z * ols[v];
    const int r = r0 + rr;
    beta[(size_t)r * 16 + v] = bvv;
    float yv = bvv * vx[(size_t)r * 16 + v];
    yv += __shfl_down(yv, 8);
    yv += __shfl_down(yv, 4);
    yv += __shfl_down(yv, 2);
    yv += __shfl_down(yv, 1);
    if (v == 0) yhat[r] = yv;
  }
}

// ---------------------------------------------------------------- launch
// ws layout (bytes)
#define OFF_PT    0u
#define OFF_SKIPB 2097152u
#define OFF_SSRC  6291456u
#define OFF_STGT  6356992u
#define OFF_VA    6422528u
#define OFF_VB    6423552u
#define OFF_SS    6424576u
#define OFF_ST    6440960u
#define OFF_TMP1  6457344u
// d_out layout (floats)
#define OUT_YHAT 65536
#define OUT_MSW  69632

extern "C" void kernel_launch(void* const* d_in, const int* in_sizes, int n_in,
                              void* d_out, int out_size, void* d_ws, size_t ws_size,
                              hipStream_t stream) {
  const float* x    = (const float*)d_in[0];
  // d_in[1] edge_distances: unused by the reference
  const float* sw   = (const float*)d_in[2];
  const float* Wp1  = (const float*)d_in[3];
  const float* as1  = (const float*)d_in[4];
  const float* at1  = (const float*)d_in[5];
  const float* Wsk  = (const float*)d_in[6];
  const float* bias1= (const float*)d_in[7];
  const float* Wp2  = (const float*)d_in[8];
  const float* as2  = (const float*)d_in[9];
  const float* at2  = (const float*)d_in[10];
  const float* W1   = (const float*)d_in[11];
  const float* b1   = (const float*)d_in[12];
  const float* W2   = (const float*)d_in[13];
  const float* b2   = (const float*)d_in[14];
  const float* W3   = (const float*)d_in[15];
  const float* b3   = (const float*)d_in[16];
  const float* ols  = (const float*)d_in[17];
  const float* vx   = (const float*)d_in[18];

  float* out = (float*)d_out;
  char* ws = (char*)d_ws;
  short* pT    = (short*)(ws + OFF_PT);
  float* skipb = (float*)(ws + OFF_SKIPB);   // becomes out_elu in place (k3)
  float* s_src = (float*)(ws + OFF_SSRC);
  float* s_tgt = (float*)(ws + OFF_STGT);
  float* va    = (float*)(ws + OFF_VA);
  float* vb    = (float*)(ws + OFF_VB);
  float* ssv   = (float*)(ws + OFF_SS);
  float* stv   = (float*)(ws + OFF_ST);
  float* tmp1  = (float*)(ws + OFF_TMP1);

  k1_proj<<<256, 256, 0, stream>>>(x, Wp1, Wsk, bias1, as1, at1, pT, skipb, s_src, s_tgt);
  k3_attn<<<256, 256, 0, stream>>>(pT, s_src, s_tgt, sw, skipb);
  k4a_vab<<<64, 256, 0, stream>>>(Wp2, as2, at2, va, vb);
  k4b_sst<<<1024, 256, 0, stream>>>(skipb, va, vb, ssv, stv);
  hipMemsetAsync(tmp1, 0, (size_t)NN * NH1 * sizeof(float), stream);
  k56_fused<<<1024, 192, 0, stream>>>(ssv, stv, sw, W1, out + OUT_MSW, tmp1);
  k7_head<<<512, 256, 0, stream>>>(tmp1, b1, W2, b2, W3, b3, ols, vx, out, out + OUT_YHAT);
}

// Round 4
// 376.497 us; speedup vs baseline: 1.1811x; 1.1811x over previous
//
#include <hip/hip_runtime.h>

// CatGWRegression on MI355X — fused GAT + GATW + regression head.
// Pipeline:
//  k1_proj : p = x@Wp1 (bf16, stored transposed p_T[c][j]), skipb = x@Wskip1+bias1,
//            s_src/s_tgt row scores (fused epilogue reductions)
//  k3_attn : flash-style masked softmax attention, e-weights computed directly in
//            MFMA A-frag layout, B-frags loaded from global p_T. No LDS/barriers.
//            Epilogue: normalize, +skip, elu -> overwrites skipb (out_elu).
//  k4a     : va = Wp2@a_src2, vb = Wp2@a_tgt2 (p2 eliminated by associativity)
//  k4b     : ss = out_elu@va, st = out_elu@vb
//  k0_w1t  : W1T[c][j] = bf16(W1[j][c]) into the skipb region (dead after k4b).
//  k5_msw  : msw = relu(ss_i+st_j)*sw -> d_out (round-0-verified code, untouched)
//  k6m     : tmp1 = msw @ W1 on the MATRIX pipe: A-frags = f2bf(msw) loaded fp32,
//            B-frags = W1T bf16, frag maps copied 1:1 from verified k3_attn.
//            grid 2048 = 256 stripes x 8 k-splits, 4 waves/block, LDS reduce +
//            atomicAdd. Replaces the fp32-VALU GEMM (133us, issue-bound at 27%
//            occupancy / 50% VALUBusy / 0 Mfma) with matrix-pipe work.
//  k7_head : beta = lrelu((tmp1+b1)@W2+b2)@W3+b3)*ols, y_hat = sum(beta*vx)
//
// NOTE: round-2's fully-fused MFMA k56 (msw compute + GEMM in one kernel) failed
// with junk in a few elements; this round isolates the GEMM (k5 verified, k6m new).
// If k6m passes, re-fuse next round; if it fails, bug is in {w1t, B-frag, reduce}.

#define NN 4096
#define FF 128
#define DD2 256
#define NH1 96

typedef __attribute__((ext_vector_type(8))) short bf16x8;
typedef __attribute__((ext_vector_type(4))) float f32x4;

__device__ __forceinline__ short f2bf(float f) {
  unsigned u = __float_as_uint(f);
  u = u + 0x7FFFu + ((u >> 16) & 1u);   // RNE
  return (short)(u >> 16);
}

// ---------------------------------------------------------------- k1
// grid 256, block 256. Block handles 16 rows x all 256 cols; K=128 streamed.
// Weights read from global (L2-hot across blocks), x tile staged in LDS.
__global__ __launch_bounds__(256) void k1_proj(
    const float* __restrict__ x, const float* __restrict__ Wp1,
    const float* __restrict__ Wsk, const float* __restrict__ bias1,
    const float* __restrict__ as1, const float* __restrict__ at1,
    short* __restrict__ pT, float* __restrict__ skipb,
    float* __restrict__ s_src, float* __restrict__ s_tgt)
{
  __shared__ float xs[16][FF];
  const int t = threadIdx.x;
  const int r0 = blockIdx.x * 16;
  for (int i = t; i < 16 * FF; i += 256)
    xs[i >> 7][i & 127] = x[(size_t)r0 * FF + i];
  __syncthreads();

  const int c = t;
  float accp[16], accs[16];
#pragma unroll
  for (int i = 0; i < 16; ++i) { accp[i] = 0.f; accs[i] = 0.f; }

  for (int k = 0; k < FF; k += 4) {
    float wp[4], wk[4];
#pragma unroll
    for (int u = 0; u < 4; ++u) {
      wp[u] = Wp1[(size_t)(k + u) * DD2 + c];
      wk[u] = Wsk[(size_t)(k + u) * DD2 + c];
    }
#pragma unroll
    for (int rr = 0; rr < 16; ++rr) {
      const float4 xv = *(const float4*)&xs[rr][k];  // uniform addr -> LDS broadcast
      accp[rr] += xv.x * wp[0] + xv.y * wp[1] + xv.z * wp[2] + xv.w * wp[3];
      accs[rr] += xv.x * wk[0] + xv.y * wk[1] + xv.z * wk[2] + xv.w * wk[3];
    }
  }

  const float asv = as1[t], atv = at1[t];  // a_src1[h][f], t = h*64+f
  const float bv = bias1[c];
  const int h = t >> 6;
  const int lane = t & 63;

#pragma unroll
  for (int rr = 0; rr < 16; ++rr)
    skipb[(size_t)(r0 + rr) * DD2 + c] = accs[rr] + bv;

  {  // p_T bf16, packed pair stores (column of p = row of p_T, contiguous in j)
    unsigned* dst = (unsigned*)(pT + (size_t)c * NN + r0);
#pragma unroll
    for (int rr = 0; rr < 16; rr += 2) {
      unsigned lo = (unsigned short)f2bf(accp[rr]);
      unsigned hi = (unsigned short)f2bf(accp[rr + 1]);
      dst[rr >> 1] = lo | (hi << 16);
    }
  }

#pragma unroll
  for (int rr = 0; rr < 16; ++rr) {  // s_src[h][i], s_tgt[h][i]
    float ps = accp[rr] * asv, pt = accp[rr] * atv;
#pragma unroll
    for (int off = 32; off > 0; off >>= 1) {
      ps += __shfl_down(ps, off);
      pt += __shfl_down(pt, off);
    }
    if (lane == 0) { s_src[h * NN + r0 + rr] = ps; s_tgt[h * NN + r0 + rr] = pt; }
  }
}

// ---------------------------------------------------------------- k3
// grid 256, block 256 (wave = head). 16 target rows per block.
// Single pass over j: e = mask ? exp(lrelu(s_src+s_tgt)) : 0, computed per-lane
// directly in A-frag layout (m=lane&15 row, k=(lane>>4)*8+u); B-frags (p_T bf16)
// loaded from global. Unnormalized accumulate + l-sum, normalize at end.
__global__ __launch_bounds__(256) void k3_attn(
    const short* __restrict__ pT, const float* __restrict__ s_src,
    const float* __restrict__ s_tgt, const float* __restrict__ sw,
    float* __restrict__ io /* in: skip+bias, out: elu(out) */)
{
  const int t = threadIdx.x;
  const int lane = t & 63;
  const int h = t >> 6;
  const int m = lane & 15;
  const int q = lane >> 4;
  const int i0 = blockIdx.x * 16;

  const float ssrc = s_src[h * NN + i0 + m];
  const float* stg = s_tgt + h * NN;
  const float* swrow = sw + (size_t)(i0 + m) * NN;
  const short* pbase = pT + (size_t)(h * 64 + m) * NN;

  f32x4 acc0 = {0.f, 0.f, 0.f, 0.f};
  f32x4 acc1 = acc0, acc2 = acc0, acc3 = acc0;
  float lsum = 0.f;

  for (int jt = 0; jt < NN; jt += 32) {
    const int jb = jt + q * 8;
    const float4 t0 = *(const float4*)(stg + jb);
    const float4 t1 = *(const float4*)(stg + jb + 4);
    const float4 w0 = *(const float4*)(swrow + jb);
    const float4 w1 = *(const float4*)(swrow + jb + 4);
    const float tj[8] = {t0.x, t0.y, t0.z, t0.w, t1.x, t1.y, t1.z, t1.w};
    const float wv[8] = {w0.x, w0.y, w0.z, w0.w, w1.x, w1.y, w1.z, w1.w};
    bf16x8 af;
    float esum = 0.f;
#pragma unroll
    for (int u = 0; u < 8; ++u) {
      float s = ssrc + tj[u];
      s = fmaxf(s, 0.2f * s);              // leaky_relu(0.2)
      float e = __expf(s);
      e = (wv[u] > 0.f) ? e : 0.f;         // mask: spatial_weights > 0
      esum += e;
      af[u] = f2bf(e);
    }
    lsum += esum;
    const bf16x8 b0 = *(const bf16x8*)(pbase + jb);
    const bf16x8 b1 = *(const bf16x8*)(pbase + 16 * NN + jb);
    const bf16x8 b2 = *(const bf16x8*)(pbase + 32 * NN + jb);
    const bf16x8 b3 = *(const bf16x8*)(pbase + 48 * NN + jb);
    acc0 = __builtin_amdgcn_mfma_f32_16x16x32_bf16(af, b0, acc0, 0, 0, 0);
    acc1 = __builtin_amdgcn_mfma_f32_16x16x32_bf16(af, b1, acc1, 0, 0, 0);
    acc2 = __builtin_amdgcn_mfma_f32_16x16x32_bf16(af, b2, acc2, 0, 0, 0);
    acc3 = __builtin_amdgcn_mfma_f32_16x16x32_bf16(af, b3, acc3, 0, 0, 0);
  }

  // l per row: reduce the 4 quads, then fetch l for C-frag rows (q*4+g)
  lsum += __shfl_xor(lsum, 16);
  lsum += __shfl_xor(lsum, 32);
  float linv[4];
#pragma unroll
  for (int g = 0; g < 4; ++g) linv[g] = 1.0f / __shfl(lsum, q * 4 + g);

  const f32x4 accs[4] = {acc0, acc1, acc2, acc3};
#pragma unroll
  for (int sub = 0; sub < 4; ++sub) {
    const int cg = h * 64 + sub * 16 + m;  // C col = lane&15
#pragma unroll
    for (int g = 0; g < 4; ++g) {
      const int r = i0 + q * 4 + g;        // C row = quad*4+reg
      float z = accs[sub][g] * linv[g] + io[(size_t)r * DD2 + cg];
      z = (z > 0.f) ? z : (__expf(z) - 1.f);   // elu
      io[(size_t)r * DD2 + cg] = z;
    }
  }
}

// ---------------------------------------------------------------- k0_w1t
// W1T[c][j] = bf16(W1[j][c]), 96 x 4096 bf16 (768 KB). grid 64, block 256.
// Tile-transpose via padded LDS. Output goes into the skipb region (dead after
// k4b); launched after k4b.
__global__ __launch_bounds__(256) void k0_w1t(
    const float* __restrict__ W1g, short* __restrict__ w1t)
{
  __shared__ short st[64 * 97];
  const int t = threadIdx.x;
  const int j0 = blockIdx.x * 64;
  for (int e = t; e < 64 * NH1; e += 256) {
    const int jj = e / NH1, c = e - jj * NH1;
    st[jj * 97 + c] = f2bf(W1g[(size_t)j0 * NH1 + e]);
  }
  __syncthreads();
  for (int o = t; o < NH1 * 32; o += 256) {      // packed pair writes
    const int c = o >> 5, jj2 = (o & 31) * 2;
    unsigned lo = (unsigned short)st[jj2 * 97 + c];
    unsigned hi = (unsigned short)st[(jj2 + 1) * 97 + c];
    *(unsigned*)(w1t + (size_t)c * NN + j0 + jj2) = lo | (hi << 16);
  }
}

// ---------------------------------------------------------------- k4a
// va = Wp2 @ a_src2, vb = Wp2 @ a_tgt2. grid 64, block 256 (wave per row).
__global__ __launch_bounds__(256) void k4a_vab(
    const float* __restrict__ Wp2, const float* __restrict__ as2,
    const float* __restrict__ at2, float* __restrict__ va, float* __restrict__ vb)
{
  const int lane = threadIdx.x & 63;
  const int w = threadIdx.x >> 6;
  const int r = blockIdx.x * 4 + w;
  const float4 wv = *(const float4*)(Wp2 + (size_t)r * DD2 + lane * 4);
  const float4 a = *(const float4*)(as2 + lane * 4);
  const float4 b = *(const float4*)(at2 + lane * 4);
  float ps = wv.x * a.x + wv.y * a.y + wv.z * a.z + wv.w * a.w;
  float pt = wv.x * b.x + wv.y * b.y + wv.z * b.z + wv.w * b.w;
#pragma unroll
  for (int off = 32; off > 0; off >>= 1) {
    ps += __shfl_down(ps, off);
    pt += __shfl_down(pt, off);
  }
  if (lane == 0) { va[r] = ps; vb[r] = pt; }
}

// ---------------------------------------------------------------- k4b
// ss[n] = out_elu[n]·va, st[n] = out_elu[n]·vb. grid 1024, wave per row.
__global__ __launch_bounds__(256) void k4b_sst(
    const float* __restrict__ oe, const float* __restrict__ va,
    const float* __restrict__ vb, float* __restrict__ ss, float* __restrict__ st)
{
  const int lane = threadIdx.x & 63;
  const int w = threadIdx.x >> 6;
  const int r = blockIdx.x * 4 + w;
  const float4 ov = *(const float4*)(oe + (size_t)r * DD2 + lane * 4);
  const float4 a = *(const float4*)(va + lane * 4);
  const float4 b = *(const float4*)(vb + lane * 4);
  float ps = ov.x * a.x + ov.y * a.y + ov.z * a.z + ov.w * a.w;
  float pt = ov.x * b.x + ov.y * b.y + ov.z * b.z + ov.w * b.w;
#pragma unroll
  for (int off = 32; off > 0; off >>= 1) {
    ps += __shfl_down(ps, off);
    pt += __shfl_down(pt, off);
  }
  if (lane == 0) { ss[r] = ps; st[r] = pt; }
}

// ---------------------------------------------------------------- k5
// msw = relu(ss_i + st_j) * sw. grid 16384, float4 per thread.
// (round-0-verified code, untouched)
__global__ __launch_bounds__(256) void k5_msw(
    const float* __restrict__ ss, const float* __restrict__ st,
    const float* __restrict__ sw, float* __restrict__ msw)
{
  const size_t gid = (size_t)blockIdx.x * 256 + threadIdx.x;
  const int i = (int)(gid >> 10);
  const int j = (int)(gid & 1023) * 4;
  const float s = ss[i];
  const float4 tv = *(const float4*)(st + j);
  const float4 wv = *(const float4*)(sw + (size_t)i * NN + j);
  float4 r;
  r.x = fmaxf(s + tv.x, 0.f) * wv.x;
  r.y = fmaxf(s + tv.y, 0.f) * wv.y;
  r.z = fmaxf(s + tv.z, 0.f) * wv.z;
  r.w = fmaxf(s + tv.w, 0.f) * wv.w;
  *(float4*)(msw + (size_t)i * NN + j) = r;
}

// ---------------------------------------------------------------- k6m
// tmp1 = msw @ W1 on the matrix pipe. M=4096 N=96 K=4096.
// grid 2048 = 256 row-stripes x 8 k-splits; block 256 = 4 waves, wave covers
// 16 rows x 128 k. A-frags: msw fp32 loads + f2bf (m=lane&15 row, k=q*8+u).
// B-frags: W1T bf16 (same map as verified k3: B[k=q*8+u][col=m] at row m+n*16).
// C-frags: col=m, row=q*4+g. Cross-wave LDS reduce, 8-way atomicAdd.
__global__ __launch_bounds__(256) void k6m_mfma(
    const float* __restrict__ msw, const short* __restrict__ w1t,
    float* __restrict__ tmp1)
{
  __shared__ float red[4][16][NH1];   // 24 KB
  const int t = threadIdx.x;
  const int w = t >> 6;
  const int lane = t & 63;
  const int m = lane & 15;
  const int q = lane >> 4;
  const int i0 = (blockIdx.x >> 3) * 16;
  const int ja = (blockIdx.x & 7) * 512 + w * 128;

  const float* arow = msw + (size_t)(i0 + m) * NN;
  const short* bbase = w1t + (size_t)m * NN;   // col c = n*16+m lives at +n*16*NN

  f32x4 acc[6];
#pragma unroll
  for (int n = 0; n < 6; ++n) acc[n] = {0.f, 0.f, 0.f, 0.f};

  for (int jt = ja; jt < ja + 128; jt += 32) {
    const int j8 = jt + q * 8;
    const float4 a0 = *(const float4*)(arow + j8);
    const float4 a1 = *(const float4*)(arow + j8 + 4);
    bf16x8 af;
    af[0] = f2bf(a0.x); af[1] = f2bf(a0.y); af[2] = f2bf(a0.z); af[3] = f2bf(a0.w);
    af[4] = f2bf(a1.x); af[5] = f2bf(a1.y); af[6] = f2bf(a1.z); af[7] = f2bf(a1.w);
#pragma unroll
    for (int n = 0; n < 6; ++n) {
      const bf16x8 bf = *(const bf16x8*)(bbase + (size_t)n * 16 * NN + j8);
      acc[n] = __builtin_amdgcn_mfma_f32_16x16x32_bf16(af, bf, acc[n], 0, 0, 0);
    }
  }

  // partials -> LDS (C layout: col = lane&15, row = q*4+g)
#pragma unroll
  for (int n = 0; n < 6; ++n)
#pragma unroll
    for (int g = 0; g < 4; ++g)
      red[w][q * 4 + g][n * 16 + m] = acc[n][g];
  __syncthreads();

  for (int e = t; e < 16 * NH1; e += 256) {
    const int r = e / NH1, c = e - r * NH1;
    const float s = red[0][r][c] + red[1][r][c] + red[2][r][c] + red[3][r][c];
    atomicAdd(&tmp1[(size_t)(i0 + r) * NH1 + c], s);
  }
}

// ---------------------------------------------------------------- k7
// beta/y_hat head. grid 512 (8 rows/block), block 256.
__global__ __launch_bounds__(256) void k7_head(
    const float* __restrict__ tmp1, const float* __restrict__ b1,
    const float* __restrict__ W2, const float* __restrict__ b2,
    const float* __restrict__ W3, const float* __restrict__ b3,
    const float* __restrict__ ols, const float* __restrict__ vx,
    float* __restrict__ beta, float* __restrict__ yhat)
{
  __shared__ float w2s[96][32];
  __shared__ float w3s[32][16];
  __shared__ float t1s[8][96];
  __shared__ float t2s[8][33];
  const int t = threadIdx.x;
  const int r0 = blockIdx.x * 8;
  for (int i = t; i < 96 * 32; i += 256) w2s[i >> 5][i & 31] = W2[i];
  for (int i = t; i < 32 * 16; i += 256) w3s[i >> 4][i & 15] = W3[i];
  for (int i = t; i < 8 * 96; i += 256) {
    const int rr = i / 96, k = i - rr * 96;
    t1s[rr][k] = tmp1[(size_t)(r0 + rr) * 96 + k] + b1[k];
  }
  __syncthreads();
  {
    const int rr = t >> 5, c2 = t & 31;
    float a = b2[c2];
    for (int k = 0; k < 96; ++k) a += t1s[rr][k] * w2s[k][c2];
    t2s[rr][c2] = a;
  }
  __syncthreads();
  const int rr = t >> 5;
  const int v = t & 31;
  if (v < 16) {
    float z = b3[v];
#pragma unroll
    for (int k = 0; k < 32; ++k) z += t2s[rr][k] * w3s[k][v];
    z = fmaxf(z, 0.2f * z);               // leaky_relu(0.2)
    const float bvv = z * ols[v];
    const int r = r0 + rr;
    beta[(size_t)r * 16 + v] = bvv;
    float yv = bvv * vx[(size_t)r * 16 + v];
    yv += __shfl_down(yv, 8);
    yv += __shfl_down(yv, 4);
    yv += __shfl_down(yv, 2);
    yv += __shfl_down(yv, 1);
    if (v == 0) yhat[r] = yv;
  }
}

// ---------------------------------------------------------------- launch
// ws layout (bytes)
#define OFF_PT    0u
#define OFF_SKIPB 2097152u    // skipb (4MB); w1t (768KB) reuses this after k4b
#define OFF_SSRC  6291456u
#define OFF_STGT  6356992u
#define OFF_VA    6422528u
#define OFF_VB    6423552u
#define OFF_SS    6424576u
#define OFF_ST    6440960u
#define OFF_TMP1  6457344u
// d_out layout (floats)
#define OUT_YHAT 65536
#define OUT_MSW  69632

extern "C" void kernel_launch(void* const* d_in, const int* in_sizes, int n_in,
                              void* d_out, int out_size, void* d_ws, size_t ws_size,
                              hipStream_t stream) {
  const float* x    = (const float*)d_in[0];
  // d_in[1] edge_distances: unused by the reference
  const float* sw   = (const float*)d_in[2];
  const float* Wp1  = (const float*)d_in[3];
  const float* as1  = (const float*)d_in[4];
  const float* at1  = (const float*)d_in[5];
  const float* Wsk  = (const float*)d_in[6];
  const float* bias1= (const float*)d_in[7];
  const float* Wp2  = (const float*)d_in[8];
  const float* as2  = (const float*)d_in[9];
  const float* at2  = (const float*)d_in[10];
  const float* W1   = (const float*)d_in[11];
  const float* b1   = (const float*)d_in[12];
  const float* W2   = (const float*)d_in[13];
  const float* b2   = (const float*)d_in[14];
  const float* W3   = (const float*)d_in[15];
  const float* b3   = (const float*)d_in[16];
  const float* ols  = (const float*)d_in[17];
  const float* vx   = (const float*)d_in[18];

  float* out = (float*)d_out;
  char* ws = (char*)d_ws;
  short* pT    = (short*)(ws + OFF_PT);
  float* skipb = (float*)(ws + OFF_SKIPB);   // becomes out_elu in place (k3)
  short* w1t   = (short*)(ws + OFF_SKIPB);   // reuses skipb space (after k4b)
  float* s_src = (float*)(ws + OFF_SSRC);
  float* s_tgt = (float*)(ws + OFF_STGT);
  float* va    = (float*)(ws + OFF_VA);
  float* vb    = (float*)(ws + OFF_VB);
  float* ssv   = (float*)(ws + OFF_SS);
  float* stv   = (float*)(ws + OFF_ST);
  float* tmp1  = (float*)(ws + OFF_TMP1);

  k1_proj<<<256, 256, 0, stream>>>(x, Wp1, Wsk, bias1, as1, at1, pT, skipb, s_src, s_tgt);
  k3_attn<<<256, 256, 0, stream>>>(pT, s_src, s_tgt, sw, skipb);
  k4a_vab<<<64, 256, 0, stream>>>(Wp2, as2, at2, va, vb);
  k4b_sst<<<1024, 256, 0, stream>>>(skipb, va, vb, ssv, stv);
  k0_w1t<<<64, 256, 0, stream>>>(W1, w1t);   // after k4b (clobbers skipb space)
  k5_msw<<<16384, 256, 0, stream>>>(ssv, stv, sw, out + OUT_MSW);
  hipMemsetAsync(tmp1, 0, (size_t)NN * NH1 * sizeof(float), stream);
  k6m_mfma<<<2048, 256, 0, stream>>>(out + OUT_MSW, w1t, tmp1);
  k7_head<<<512, 256, 0, stream>>>(tmp1, b1, W2, b2, W3, b3, ols, vx, out, out + OUT_YHAT);
}

// Round 5
// 376.071 us; speedup vs baseline: 1.1824x; 1.0011x over previous
//
#include <hip/hip_runtime.h>

// CatGWRegression on MI355X — fused GAT + GATW + regression head.
// Pipeline:
//  k1_proj : p = x@Wp1 (bf16, stored transposed p_T[c][j]), skipb = x@Wskip1+bias1,
//            s_src/s_tgt row scores (fused epilogue reductions)
//  k3_attn : flash-style masked softmax attention, e-weights computed directly in
//            MFMA A-frag layout, B-frags loaded from global p_T.
//            Block = 1024 thr = 16 waves = 4 heads x 4 j-quarters (j-split fixes
//            the 10.7% occupancy / latency-bound profile of the 4-wave version:
//            109us at 22% VALUBusy). Partials combined in LDS; epilogue
//            normalize, +skip, elu -> overwrites skipb (out_elu).
//  k4a     : va = Wp2@a_src2, vb = Wp2@a_tgt2 (p2 eliminated by associativity)
//  k4b     : ss = out_elu@va, st = out_elu@vb
//  k0_w1t  : W1T[c][j] = bf16(W1[j][c]) into the skipb region (dead after k4b).
//  k5_msw  : msw = relu(ss_i+st_j)*sw -> d_out (round-0-verified code, untouched)
//  k6m     : tmp1 = msw @ W1 on the MATRIX pipe (verified round 4).
//  k7_head : beta = lrelu((tmp1+b1)@W2+b2)@W3+b3)*ols, y_hat = sum(beta*vx)

#define NN 4096
#define FF 128
#define DD2 256
#define NH1 96

typedef __attribute__((ext_vector_type(8))) short bf16x8;
typedef __attribute__((ext_vector_type(4))) float f32x4;

__device__ __forceinline__ short f2bf(float f) {
  unsigned u = __float_as_uint(f);
  u = u + 0x7FFFu + ((u >> 16) & 1u);   // RNE
  return (short)(u >> 16);
}

// ---------------------------------------------------------------- k1
// grid 256, block 256. Block handles 16 rows x all 256 cols; K=128 streamed.
// Weights read from global (L2-hot across blocks), x tile staged in LDS.
__global__ __launch_bounds__(256) void k1_proj(
    const float* __restrict__ x, const float* __restrict__ Wp1,
    const float* __restrict__ Wsk, const float* __restrict__ bias1,
    const float* __restrict__ as1, const float* __restrict__ at1,
    short* __restrict__ pT, float* __restrict__ skipb,
    float* __restrict__ s_src, float* __restrict__ s_tgt)
{
  __shared__ float xs[16][FF];
  const int t = threadIdx.x;
  const int r0 = blockIdx.x * 16;
  for (int i = t; i < 16 * FF; i += 256)
    xs[i >> 7][i & 127] = x[(size_t)r0 * FF + i];
  __syncthreads();

  const int c = t;
  float accp[16], accs[16];
#pragma unroll
  for (int i = 0; i < 16; ++i) { accp[i] = 0.f; accs[i] = 0.f; }

  for (int k = 0; k < FF; k += 4) {
    float wp[4], wk[4];
#pragma unroll
    for (int u = 0; u < 4; ++u) {
      wp[u] = Wp1[(size_t)(k + u) * DD2 + c];
      wk[u] = Wsk[(size_t)(k + u) * DD2 + c];
    }
#pragma unroll
    for (int rr = 0; rr < 16; ++rr) {
      const float4 xv = *(const float4*)&xs[rr][k];  // uniform addr -> LDS broadcast
      accp[rr] += xv.x * wp[0] + xv.y * wp[1] + xv.z * wp[2] + xv.w * wp[3];
      accs[rr] += xv.x * wk[0] + xv.y * wk[1] + xv.z * wk[2] + xv.w * wk[3];
    }
  }

  const float asv = as1[t], atv = at1[t];  // a_src1[h][f], t = h*64+f
  const float bv = bias1[c];
  const int h = t >> 6;
  const int lane = t & 63;

#pragma unroll
  for (int rr = 0; rr < 16; ++rr)
    skipb[(size_t)(r0 + rr) * DD2 + c] = accs[rr] + bv;

  {  // p_T bf16, packed pair stores (column of p = row of p_T, contiguous in j)
    unsigned* dst = (unsigned*)(pT + (size_t)c * NN + r0);
#pragma unroll
    for (int rr = 0; rr < 16; rr += 2) {
      unsigned lo = (unsigned short)f2bf(accp[rr]);
      unsigned hi = (unsigned short)f2bf(accp[rr + 1]);
      dst[rr >> 1] = lo | (hi << 16);
    }
  }

#pragma unroll
  for (int rr = 0; rr < 16; ++rr) {  // s_src[h][i], s_tgt[h][i]
    float ps = accp[rr] * asv, pt = accp[rr] * atv;
#pragma unroll
    for (int off = 32; off > 0; off >>= 1) {
      ps += __shfl_down(ps, off);
      pt += __shfl_down(pt, off);
    }
    if (lane == 0) { s_src[h * NN + r0 + rr] = ps; s_tgt[h * NN + r0 + rr] = pt; }
  }
}

// ---------------------------------------------------------------- k3
// grid 256, block 1024 = 16 waves: wave w handles head h=w&3, j-quarter qd=w>>2.
// Loop body identical to the verified 4-wave version, over 1024 j per wave.
// Unnormalized acc + lsum are linear in j -> per-wave partials to LDS, then a
// block-wide combine: O = sum_q part, l = sum_q lsum, normalize, +skip, elu.
__global__ __launch_bounds__(1024) void k3_attn(
    const short* __restrict__ pT, const float* __restrict__ s_src,
    const float* __restrict__ s_tgt, const float* __restrict__ sw,
    float* __restrict__ io /* in: skip+bias, out: elu(out) */)
{
  __shared__ float part[16][16][65];   // [wave][row][col-in-head], +1 pad
  __shared__ float lsum_s[16][16];     // [wave][row]
  const int t = threadIdx.x;
  const int lane = t & 63;
  const int w = t >> 6;     // 0..15
  const int h = w & 3;      // head
  const int qd = w >> 2;    // j-quarter
  const int m = lane & 15;
  const int q = lane >> 4;
  const int i0 = blockIdx.x * 16;

  const float ssrc = s_src[h * NN + i0 + m];
  const float* stg = s_tgt + h * NN;
  const float* swrow = sw + (size_t)(i0 + m) * NN;
  const short* pbase = pT + (size_t)(h * 64 + m) * NN;

  f32x4 acc0 = {0.f, 0.f, 0.f, 0.f};
  f32x4 acc1 = acc0, acc2 = acc0, acc3 = acc0;
  float lsum = 0.f;

  const int jq = qd * 1024;
  for (int jt = jq; jt < jq + 1024; jt += 32) {
    const int jb = jt + q * 8;
    const float4 t0 = *(const float4*)(stg + jb);
    const float4 t1 = *(const float4*)(stg + jb + 4);
    const float4 w0 = *(const float4*)(swrow + jb);
    const float4 w1 = *(const float4*)(swrow + jb + 4);
    const float tj[8] = {t0.x, t0.y, t0.z, t0.w, t1.x, t1.y, t1.z, t1.w};
    const float wv[8] = {w0.x, w0.y, w0.z, w0.w, w1.x, w1.y, w1.z, w1.w};
    bf16x8 af;
    float esum = 0.f;
#pragma unroll
    for (int u = 0; u < 8; ++u) {
      float s = ssrc + tj[u];
      s = fmaxf(s, 0.2f * s);              // leaky_relu(0.2)
      float e = __expf(s);
      e = (wv[u] > 0.f) ? e : 0.f;         // mask: spatial_weights > 0
      esum += e;
      af[u] = f2bf(e);
    }
    lsum += esum;
    const bf16x8 b0 = *(const bf16x8*)(pbase + jb);
    const bf16x8 b1 = *(const bf16x8*)(pbase + 16 * NN + jb);
    const bf16x8 b2 = *(const bf16x8*)(pbase + 32 * NN + jb);
    const bf16x8 b3 = *(const bf16x8*)(pbase + 48 * NN + jb);
    acc0 = __builtin_amdgcn_mfma_f32_16x16x32_bf16(af, b0, acc0, 0, 0, 0);
    acc1 = __builtin_amdgcn_mfma_f32_16x16x32_bf16(af, b1, acc1, 0, 0, 0);
    acc2 = __builtin_amdgcn_mfma_f32_16x16x32_bf16(af, b2, acc2, 0, 0, 0);
    acc3 = __builtin_amdgcn_mfma_f32_16x16x32_bf16(af, b3, acc3, 0, 0, 0);
  }

  // per-wave l partial per row (xor over the 4 q-lanes of each row)
  lsum += __shfl_xor(lsum, 16);
  lsum += __shfl_xor(lsum, 32);
  if (q == 0) lsum_s[w][m] = lsum;

  // per-wave C partials -> LDS (C layout: col = lane&15, row = q*4+g)
  const f32x4 accs[4] = {acc0, acc1, acc2, acc3};
#pragma unroll
  for (int sub = 0; sub < 4; ++sub)
#pragma unroll
    for (int g = 0; g < 4; ++g)
      part[w][q * 4 + g][sub * 16 + m] = accs[sub][g];
  __syncthreads();

  // combine quarters + normalize + skip + elu. 16x256 elements / 1024 threads.
  for (int e = t; e < 16 * 256; e += 1024) {
    const int r = e >> 8;          // row in stripe
    const int c = e & 255;         // output column
    const int hh = c >> 6, cc = c & 63;
    float o = 0.f, l = 0.f;
#pragma unroll
    for (int qq = 0; qq < 4; ++qq) {
      o += part[qq * 4 + hh][r][cc];
      l += lsum_s[qq * 4 + hh][r];
    }
    float z = o / l + io[(size_t)(i0 + r) * DD2 + c];
    z = (z > 0.f) ? z : (__expf(z) - 1.f);   // elu
    io[(size_t)(i0 + r) * DD2 + c] = z;
  }
}

// ---------------------------------------------------------------- k0_w1t
// W1T[c][j] = bf16(W1[j][c]), 96 x 4096 bf16 (768 KB). grid 64, block 256.
// Tile-transpose via padded LDS. Output goes into the skipb region (dead after
// k4b); launched after k4b.
__global__ __launch_bounds__(256) void k0_w1t(
    const float* __restrict__ W1g, short* __restrict__ w1t)
{
  __shared__ short st[64 * 97];
  const int t = threadIdx.x;
  const int j0 = blockIdx.x * 64;
  for (int e = t; e < 64 * NH1; e += 256) {
    const int jj = e / NH1, c = e - jj * NH1;
    st[jj * 97 + c] = f2bf(W1g[(size_t)j0 * NH1 + e]);
  }
  __syncthreads();
  for (int o = t; o < NH1 * 32; o += 256) {      // packed pair writes
    const int c = o >> 5, jj2 = (o & 31) * 2;
    unsigned lo = (unsigned short)st[jj2 * 97 + c];
    unsigned hi = (unsigned short)st[(jj2 + 1) * 97 + c];
    *(unsigned*)(w1t + (size_t)c * NN + j0 + jj2) = lo | (hi << 16);
  }
}

// ---------------------------------------------------------------- k4a
// va = Wp2 @ a_src2, vb = Wp2 @ a_tgt2. grid 64, block 256 (wave per row).
__global__ __launch_bounds__(256) void k4a_vab(
    const float* __restrict__ Wp2, const float* __restrict__ as2,
    const float* __restrict__ at2, float* __restrict__ va, float* __restrict__ vb)
{
  const int lane = threadIdx.x & 63;
  const int w = threadIdx.x >> 6;
  const int r = blockIdx.x * 4 + w;
  const float4 wv = *(const float4*)(Wp2 + (size_t)r * DD2 + lane * 4);
  const float4 a = *(const float4*)(as2 + lane * 4);
  const float4 b = *(const float4*)(at2 + lane * 4);
  float ps = wv.x * a.x + wv.y * a.y + wv.z * a.z + wv.w * a.w;
  float pt = wv.x * b.x + wv.y * b.y + wv.z * b.z + wv.w * b.w;
#pragma unroll
  for (int off = 32; off > 0; off >>= 1) {
    ps += __shfl_down(ps, off);
    pt += __shfl_down(pt, off);
  }
  if (lane == 0) { va[r] = ps; vb[r] = pt; }
}

// ---------------------------------------------------------------- k4b
// ss[n] = out_elu[n]·va, st[n] = out_elu[n]·vb. grid 1024, wave per row.
__global__ __launch_bounds__(256) void k4b_sst(
    const float* __restrict__ oe, const float* __restrict__ va,
    const float* __restrict__ vb, float* __restrict__ ss, float* __restrict__ st)
{
  const int lane = threadIdx.x & 63;
  const int w = threadIdx.x >> 6;
  const int r = blockIdx.x * 4 + w;
  const float4 ov = *(const float4*)(oe + (size_t)r * DD2 + lane * 4);
  const float4 a = *(const float4*)(va + lane * 4);
  const float4 b = *(const float4*)(vb + lane * 4);
  float ps = ov.x * a.x + ov.y * a.y + ov.z * a.z + ov.w * a.w;
  float pt = ov.x * b.x + ov.y * b.y + ov.z * b.z + ov.w * b.w;
#pragma unroll
  for (int off = 32; off > 0; off >>= 1) {
    ps += __shfl_down(ps, off);
    pt += __shfl_down(pt, off);
  }
  if (lane == 0) { ss[r] = ps; st[r] = pt; }
}

// ---------------------------------------------------------------- k5
// msw = relu(ss_i + st_j) * sw. grid 16384, float4 per thread.
// (round-0-verified code, untouched)
__global__ __launch_bounds__(256) void k5_msw(
    const float* __restrict__ ss, const float* __restrict__ st,
    const float* __restrict__ sw, float* __restrict__ msw)
{
  const size_t gid = (size_t)blockIdx.x * 256 + threadIdx.x;
  const int i = (int)(gid >> 10);
  const int j = (int)(gid & 1023) * 4;
  const float s = ss[i];
  const float4 tv = *(const float4*)(st + j);
  const float4 wv = *(const float4*)(sw + (size_t)i * NN + j);
  float4 r;
  r.x = fmaxf(s + tv.x, 0.f) * wv.x;
  r.y = fmaxf(s + tv.y, 0.f) * wv.y;
  r.z = fmaxf(s + tv.z, 0.f) * wv.z;
  r.w = fmaxf(s + tv.w, 0.f) * wv.w;
  *(float4*)(msw + (size_t)i * NN + j) = r;
}

// ---------------------------------------------------------------- k6m
// tmp1 = msw @ W1 on the matrix pipe. M=4096 N=96 K=4096.
// grid 2048 = 256 row-stripes x 8 k-splits; block 256 = 4 waves, wave covers
// 16 rows x 128 k. A-frags: msw fp32 loads + f2bf (m=lane&15 row, k=q*8+u).
// B-frags: W1T bf16 (same map as verified k3: B[k=q*8+u][col=m] at row m+n*16).
// C-frags: col=m, row=q*4+g. Cross-wave LDS reduce, 8-way atomicAdd.
__global__ __launch_bounds__(256) void k6m_mfma(
    const float* __restrict__ msw, const short* __restrict__ w1t,
    float* __restrict__ tmp1)
{
  __shared__ float red[4][16][NH1];   // 24 KB
  const int t = threadIdx.x;
  const int w = t >> 6;
  const int lane = t & 63;
  const int m = lane & 15;
  const int q = lane >> 4;
  const int i0 = (blockIdx.x >> 3) * 16;
  const int ja = (blockIdx.x & 7) * 512 + w * 128;

  const float* arow = msw + (size_t)(i0 + m) * NN;
  const short* bbase = w1t + (size_t)m * NN;   // col c = n*16+m lives at +n*16*NN

  f32x4 acc[6];
#pragma unroll
  for (int n = 0; n < 6; ++n) acc[n] = {0.f, 0.f, 0.f, 0.f};

  for (int jt = ja; jt < ja + 128; jt += 32) {
    const int j8 = jt + q * 8;
    const float4 a0 = *(const float4*)(arow + j8);
    const float4 a1 = *(const float4*)(arow + j8 + 4);
    bf16x8 af;
    af[0] = f2bf(a0.x); af[1] = f2bf(a0.y); af[2] = f2bf(a0.z); af[3] = f2bf(a0.w);
    af[4] = f2bf(a1.x); af[5] = f2bf(a1.y); af[6] = f2bf(a1.z); af[7] = f2bf(a1.w);
#pragma unroll
    for (int n = 0; n < 6; ++n) {
      const bf16x8 bf = *(const bf16x8*)(bbase + (size_t)n * 16 * NN + j8);
      acc[n] = __builtin_amdgcn_mfma_f32_16x16x32_bf16(af, bf, acc[n], 0, 0, 0);
    }
  }

  // partials -> LDS (C layout: col = lane&15, row = q*4+g)
#pragma unroll
  for (int n = 0; n < 6; ++n)
#pragma unroll
    for (int g = 0; g < 4; ++g)
      red[w][q * 4 + g][n * 16 + m] = acc[n][g];
  __syncthreads();

  for (int e = t; e < 16 * NH1; e += 256) {
    const int r = e / NH1, c = e - r * NH1;
    const float s = red[0][r][c] + red[1][r][c] + red[2][r][c] + red[3][r][c];
    atomicAdd(&tmp1[(size_t)(i0 + r) * NH1 + c], s);
  }
}

// ---------------------------------------------------------------- k7
// beta/y_hat head. grid 512 (8 rows/block), block 256.
__global__ __launch_bounds__(256) void k7_head(
    const float* __restrict__ tmp1, const float* __restrict__ b1,
    const float* __restrict__ W2, const float* __restrict__ b2,
    const float* __restrict__ W3, const float* __restrict__ b3,
    const float* __restrict__ ols, const float* __restrict__ vx,
    float* __restrict__ beta, float* __restrict__ yhat)
{
  __shared__ float w2s[96][32];
  __shared__ float w3s[32][16];
  __shared__ float t1s[8][96];
  __shared__ float t2s[8][33];
  const int t = threadIdx.x;
  const int r0 = blockIdx.x * 8;
  for (int i = t; i < 96 * 32; i += 256) w2s[i >> 5][i & 31] = W2[i];
  for (int i = t; i < 32 * 16; i += 256) w3s[i >> 4][i & 15] = W3[i];
  for (int i = t; i < 8 * 96; i += 256) {
    const int rr = i / 96, k = i - rr * 96;
    t1s[rr][k] = tmp1[(size_t)(r0 + rr) * 96 + k] + b1[k];
  }
  __syncthreads();
  {
    const int rr = t >> 5, c2 = t & 31;
    float a = b2[c2];
    for (int k = 0; k < 96; ++k) a += t1s[rr][k] * w2s[k][c2];
    t2s[rr][c2] = a;
  }
  __syncthreads();
  const int rr = t >> 5;
  const int v = t & 31;
  if (v < 16) {
    float z = b3[v];
#pragma unroll
    for (int k = 0; k < 32; ++k) z += t2s[rr][k] * w3s[k][v];
    z = fmaxf(z, 0.2f * z);               // leaky_relu(0.2)
    const float bvv = z * ols[v];
    const int r = r0 + rr;
    beta[(size_t)r * 16 + v] = bvv;
    float yv = bvv * vx[(size_t)r * 16 + v];
    yv += __shfl_down(yv, 8);
    yv += __shfl_down(yv, 4);
    yv += __shfl_down(yv, 2);
    yv += __shfl_down(yv, 1);
    if (v == 0) yhat[r] = yv;
  }
}

// ---------------------------------------------------------------- launch
// ws layout (bytes)
#define OFF_PT    0u
#define OFF_SKIPB 2097152u    // skipb (4MB); w1t (768KB) reuses this after k4b
#define OFF_SSRC  6291456u
#define OFF_STGT  6356992u
#define OFF_VA    6422528u
#define OFF_VB    6423552u
#define OFF_SS    6424576u
#define OFF_ST    6440960u
#define OFF_TMP1  6457344u
// d_out layout (floats)
#define OUT_YHAT 65536
#define OUT_MSW  69632

extern "C" void kernel_launch(void* const* d_in, const int* in_sizes, int n_in,
                              void* d_out, int out_size, void* d_ws, size_t ws_size,
                              hipStream_t stream) {
  const float* x    = (const float*)d_in[0];
  // d_in[1] edge_distances: unused by the reference
  const float* sw   = (const float*)d_in[2];
  const float* Wp1  = (const float*)d_in[3];
  const float* as1  = (const float*)d_in[4];
  const float* at1  = (const float*)d_in[5];
  const float* Wsk  = (const float*)d_in[6];
  const float* bias1= (const float*)d_in[7];
  const float* Wp2  = (const float*)d_in[8];
  const float* as2  = (const float*)d_in[9];
  const float* at2  = (const float*)d_in[10];
  const float* W1   = (const float*)d_in[11];
  const float* b1   = (const float*)d_in[12];
  const float* W2   = (const float*)d_in[13];
  const float* b2   = (const float*)d_in[14];
  const float* W3   = (const float*)d_in[15];
  const float* b3   = (const float*)d_in[16];
  const float* ols  = (const float*)d_in[17];
  const float* vx   = (const float*)d_in[18];

  float* out = (float*)d_out;
  char* ws = (char*)d_ws;
  short* pT    = (short*)(ws + OFF_PT);
  float* skipb = (float*)(ws + OFF_SKIPB);   // becomes out_elu in place (k3)
  short* w1t   = (short*)(ws + OFF_SKIPB);   // reuses skipb space (after k4b)
  float* s_src = (float*)(ws + OFF_SSRC);
  float* s_tgt = (float*)(ws + OFF_STGT);
  float* va    = (float*)(ws + OFF_VA);
  float* vb    = (float*)(ws + OFF_VB);
  float* ssv   = (float*)(ws + OFF_SS);
  float* stv   = (float*)(ws + OFF_ST);
  float* tmp1  = (float*)(ws + OFF_TMP1);

  k1_proj<<<256, 256, 0, stream>>>(x, Wp1, Wsk, bias1, as1, at1, pT, skipb, s_src, s_tgt);
  k3_attn<<<256, 1024, 0, stream>>>(pT, s_src, s_tgt, sw, skipb);
  k4a_vab<<<64, 256, 0, stream>>>(Wp2, as2, at2, va, vb);
  k4b_sst<<<1024, 256, 0, stream>>>(skipb, va, vb, ssv, stv);
  k0_w1t<<<64, 256, 0, stream>>>(W1, w1t);   // after k4b (clobbers skipb space)
  k5_msw<<<16384, 256, 0, stream>>>(ssv, stv, sw, out + OUT_MSW);
  hipMemsetAsync(tmp1, 0, (size_t)NN * NH1 * sizeof(float), stream);
  k6m_mfma<<<2048, 256, 0, stream>>>(out + OUT_MSW, w1t, tmp1);
  k7_head<<<512, 256, 0, stream>>>(tmp1, b1, W2, b2, W3, b3, ols, vx, out, out + OUT_YHAT);
}

// Round 6
// 369.726 us; speedup vs baseline: 1.2027x; 1.0172x over previous
//
#include <hip/hip_runtime.h>

// CatGWRegression on MI355X — fused GAT + GATW + regression head.
// Pipeline:
//  k1_proj : p = x@Wp1 (bf16, stored transposed p_T[c][j]), skipb = x@Wskip1+bias1,
//            s_src/s_tgt row scores (fused epilogue reductions)
//  k2_mask : bitmask[i][j] = (sw[i][j] > 0), 4096x128 u32 (2 MB), written into the
//            msw region of d_out (k5 fully overwrites it later). Streams sw once;
//            turns k3's per-iter 32B/lane HBM-latency sw read into a 4B L2 read.
//  k3_attn : flash-style masked softmax attention, e-weights computed directly in
//            MFMA A-frag layout, B-frags from global p_T (L2-resident). 16 waves =
//            4 heads x 4 j-quarters; mask from bitmask; 1-deep manual prefetch
//            pipeline (VGPR 36 was serializing iterations). LDS combine; epilogue
//            normalize, +skip, elu -> overwrites skipb (out_elu).
//  k4a     : va = Wp2@a_src2, vb = Wp2@a_tgt2 (p2 eliminated by associativity)
//  k4b     : ss = out_elu@va, st = out_elu@vb
//  k0_w1t  : W1T[c][j] = bf16(W1[j][c]) into the skipb region (dead after k4b).
//  k5_msw  : msw = relu(ss_i+st_j)*sw -> d_out (overwrites the bitmask scratch)
//  k6m     : tmp1 = msw @ W1 on the MATRIX pipe (verified round 4).
//  k7_head : beta = lrelu((tmp1+b1)@W2+b2)@W3+b3)*ols, y_hat = sum(beta*vx)

#define NN 4096
#define FF 128
#define DD2 256
#define NH1 96

typedef __attribute__((ext_vector_type(8))) short bf16x8;
typedef __attribute__((ext_vector_type(4))) float f32x4;

__device__ __forceinline__ short f2bf(float f) {
  unsigned u = __float_as_uint(f);
  u = u + 0x7FFFu + ((u >> 16) & 1u);   // RNE
  return (short)(u >> 16);
}

// ---------------------------------------------------------------- k1
// grid 256, block 256. Block handles 16 rows x all 256 cols; K=128 streamed.
// Weights read from global (L2-hot across blocks), x tile staged in LDS.
__global__ __launch_bounds__(256) void k1_proj(
    const float* __restrict__ x, const float* __restrict__ Wp1,
    const float* __restrict__ Wsk, const float* __restrict__ bias1,
    const float* __restrict__ as1, const float* __restrict__ at1,
    short* __restrict__ pT, float* __restrict__ skipb,
    float* __restrict__ s_src, float* __restrict__ s_tgt)
{
  __shared__ float xs[16][FF];
  const int t = threadIdx.x;
  const int r0 = blockIdx.x * 16;
  for (int i = t; i < 16 * FF; i += 256)
    xs[i >> 7][i & 127] = x[(size_t)r0 * FF + i];
  __syncthreads();

  const int c = t;
  float accp[16], accs[16];
#pragma unroll
  for (int i = 0; i < 16; ++i) { accp[i] = 0.f; accs[i] = 0.f; }

  for (int k = 0; k < FF; k += 4) {
    float wp[4], wk[4];
#pragma unroll
    for (int u = 0; u < 4; ++u) {
      wp[u] = Wp1[(size_t)(k + u) * DD2 + c];
      wk[u] = Wsk[(size_t)(k + u) * DD2 + c];
    }
#pragma unroll
    for (int rr = 0; rr < 16; ++rr) {
      const float4 xv = *(const float4*)&xs[rr][k];  // uniform addr -> LDS broadcast
      accp[rr] += xv.x * wp[0] + xv.y * wp[1] + xv.z * wp[2] + xv.w * wp[3];
      accs[rr] += xv.x * wk[0] + xv.y * wk[1] + xv.z * wk[2] + xv.w * wk[3];
    }
  }

  const float asv = as1[t], atv = at1[t];  // a_src1[h][f], t = h*64+f
  const float bv = bias1[c];
  const int h = t >> 6;
  const int lane = t & 63;

#pragma unroll
  for (int rr = 0; rr < 16; ++rr)
    skipb[(size_t)(r0 + rr) * DD2 + c] = accs[rr] + bv;

  {  // p_T bf16, packed pair stores (column of p = row of p_T, contiguous in j)
    unsigned* dst = (unsigned*)(pT + (size_t)c * NN + r0);
#pragma unroll
    for (int rr = 0; rr < 16; rr += 2) {
      unsigned lo = (unsigned short)f2bf(accp[rr]);
      unsigned hi = (unsigned short)f2bf(accp[rr + 1]);
      dst[rr >> 1] = lo | (hi << 16);
    }
  }

#pragma unroll
  for (int rr = 0; rr < 16; ++rr) {  // s_src[h][i], s_tgt[h][i]
    float ps = accp[rr] * asv, pt = accp[rr] * atv;
#pragma unroll
    for (int off = 32; off > 0; off >>= 1) {
      ps += __shfl_down(ps, off);
      pt += __shfl_down(pt, off);
    }
    if (lane == 0) { s_src[h * NN + r0 + rr] = ps; s_tgt[h * NN + r0 + rr] = pt; }
  }
}

// ---------------------------------------------------------------- k2
// bitmask of sw>0. grid 2048, block 256. Thread g covers row = g>>7,
// j in [ (g&127)*32, +32 ): 8 float4 reads -> one u32 (bit u = j offset u).
__global__ __launch_bounds__(256) void k2_mask(
    const float* __restrict__ sw, unsigned* __restrict__ mask)
{
  const int g = blockIdx.x * 256 + threadIdx.x;
  const float* p = sw + (size_t)g * 32;
  unsigned bits = 0;
#pragma unroll
  for (int u = 0; u < 8; ++u) {
    const float4 v = *(const float4*)(p + u * 4);
    const unsigned nib = (v.x > 0.f ? 1u : 0u) | (v.y > 0.f ? 2u : 0u)
                       | (v.z > 0.f ? 4u : 0u) | (v.w > 0.f ? 8u : 0u);
    bits |= nib << (u * 4);
  }
  mask[g] = bits;
}

// ---------------------------------------------------------------- k3
// grid 256, block 1024 = 16 waves: wave w handles head h=w&3, j-quarter qd=w>>2.
// All in-loop loads are L2-resident (mask 2MB, s_tgt 64KB, pT 2MB). 1-deep
// manual prefetch pipeline overlaps next-iter loads with current compute.
#define K3_STEP(T0, T1, MW, B0, B1, B2, B3) do {                               \
    const float tjv[8] = {T0.x, T0.y, T0.z, T0.w, T1.x, T1.y, T1.z, T1.w};     \
    const unsigned mb = (MW) >> (q * 8);                                       \
    bf16x8 af; float esum = 0.f;                                               \
    _Pragma("unroll")                                                          \
    for (int u = 0; u < 8; ++u) {                                              \
      float s = ssrc + tjv[u];                                                 \
      s = fmaxf(s, 0.2f * s);                    /* leaky_relu(0.2) */         \
      const float e = ((mb >> u) & 1u) ? __expf(s) : 0.f;                      \
      esum += e; af[u] = f2bf(e);                                              \
    }                                                                          \
    lsum += esum;                                                              \
    acc0 = __builtin_amdgcn_mfma_f32_16x16x32_bf16(af, B0, acc0, 0, 0, 0);     \
    acc1 = __builtin_amdgcn_mfma_f32_16x16x32_bf16(af, B1, acc1, 0, 0, 0);     \
    acc2 = __builtin_amdgcn_mfma_f32_16x16x32_bf16(af, B2, acc2, 0, 0, 0);     \
    acc3 = __builtin_amdgcn_mfma_f32_16x16x32_bf16(af, B3, acc3, 0, 0, 0);     \
  } while (0)

__global__ __launch_bounds__(1024) void k3_attn(
    const short* __restrict__ pT, const float* __restrict__ s_src,
    const float* __restrict__ s_tgt, const unsigned* __restrict__ mask,
    float* __restrict__ io /* in: skip+bias, out: elu(out) */)
{
  __shared__ float part[16][16][65];   // [wave][row][col-in-head], +1 pad
  __shared__ float lsum_s[16][16];     // [wave][row]
  const int t = threadIdx.x;
  const int lane = t & 63;
  const int w = t >> 6;     // 0..15
  const int h = w & 3;      // head
  const int qd = w >> 2;    // j-quarter
  const int m = lane & 15;
  const int q = lane >> 4;
  const int i0 = blockIdx.x * 16;

  const float ssrc = s_src[h * NN + i0 + m];
  const float* stg = s_tgt + h * NN;
  const unsigned* mrow = mask + (size_t)(i0 + m) * 128;
  const short* pbase = pT + (size_t)(h * 64 + m) * NN;

  f32x4 acc0 = {0.f, 0.f, 0.f, 0.f};
  f32x4 acc1 = acc0, acc2 = acc0, acc3 = acc0;
  float lsum = 0.f;

  const int jq = qd * 1024;
  {
    const int jb = jq + q * 8;
    float4 ct0 = *(const float4*)(stg + jb);
    float4 ct1 = *(const float4*)(stg + jb + 4);
    unsigned cmw = mrow[jq >> 5];
    bf16x8 cb0 = *(const bf16x8*)(pbase + jb);
    bf16x8 cb1 = *(const bf16x8*)(pbase + 16 * NN + jb);
    bf16x8 cb2 = *(const bf16x8*)(pbase + 32 * NN + jb);
    bf16x8 cb3 = *(const bf16x8*)(pbase + 48 * NN + jb);

    for (int jt = jq; jt < jq + 1024 - 32; jt += 32) {
      const int njb = jt + 32 + q * 8;
      const float4 nt0 = *(const float4*)(stg + njb);
      const float4 nt1 = *(const float4*)(stg + njb + 4);
      const unsigned nmw = mrow[(jt + 32) >> 5];
      const bf16x8 nb0 = *(const bf16x8*)(pbase + njb);
      const bf16x8 nb1 = *(const bf16x8*)(pbase + 16 * NN + njb);
      const bf16x8 nb2 = *(const bf16x8*)(pbase + 32 * NN + njb);
      const bf16x8 nb3 = *(const bf16x8*)(pbase + 48 * NN + njb);
      K3_STEP(ct0, ct1, cmw, cb0, cb1, cb2, cb3);
      ct0 = nt0; ct1 = nt1; cmw = nmw;
      cb0 = nb0; cb1 = nb1; cb2 = nb2; cb3 = nb3;
    }
    K3_STEP(ct0, ct1, cmw, cb0, cb1, cb2, cb3);
  }

  // per-wave l partial per row (xor over the 4 q-lanes of each row)
  lsum += __shfl_xor(lsum, 16);
  lsum += __shfl_xor(lsum, 32);
  if (q == 0) lsum_s[w][m] = lsum;

  // per-wave C partials -> LDS (C layout: col = lane&15, row = q*4+g)
  const f32x4 accs[4] = {acc0, acc1, acc2, acc3};
#pragma unroll
  for (int sub = 0; sub < 4; ++sub)
#pragma unroll
    for (int g = 0; g < 4; ++g)
      part[w][q * 4 + g][sub * 16 + m] = accs[sub][g];
  __syncthreads();

  // combine quarters + normalize + skip + elu. 16x256 elements / 1024 threads.
  for (int e = t; e < 16 * 256; e += 1024) {
    const int r = e >> 8;          // row in stripe
    const int c = e & 255;         // output column
    const int hh = c >> 6, cc = c & 63;
    float o = 0.f, l = 0.f;
#pragma unroll
    for (int qq = 0; qq < 4; ++qq) {
      o += part[qq * 4 + hh][r][cc];
      l += lsum_s[qq * 4 + hh][r];
    }
    float z = o / l + io[(size_t)(i0 + r) * DD2 + c];
    z = (z > 0.f) ? z : (__expf(z) - 1.f);   // elu
    io[(size_t)(i0 + r) * DD2 + c] = z;
  }
}

// ---------------------------------------------------------------- k0_w1t
// W1T[c][j] = bf16(W1[j][c]), 96 x 4096 bf16 (768 KB). grid 64, block 256.
// Tile-transpose via padded LDS. Output goes into the skipb region (dead after
// k4b); launched after k4b.
__global__ __launch_bounds__(256) void k0_w1t(
    const float* __restrict__ W1g, short* __restrict__ w1t)
{
  __shared__ short st[64 * 97];
  const int t = threadIdx.x;
  const int j0 = blockIdx.x * 64;
  for (int e = t; e < 64 * NH1; e += 256) {
    const int jj = e / NH1, c = e - jj * NH1;
    st[jj * 97 + c] = f2bf(W1g[(size_t)j0 * NH1 + e]);
  }
  __syncthreads();
  for (int o = t; o < NH1 * 32; o += 256) {      // packed pair writes
    const int c = o >> 5, jj2 = (o & 31) * 2;
    unsigned lo = (unsigned short)st[jj2 * 97 + c];
    unsigned hi = (unsigned short)st[(jj2 + 1) * 97 + c];
    *(unsigned*)(w1t + (size_t)c * NN + j0 + jj2) = lo | (hi << 16);
  }
}

// ---------------------------------------------------------------- k4a
// va = Wp2 @ a_src2, vb = Wp2 @ a_tgt2. grid 64, block 256 (wave per row).
__global__ __launch_bounds__(256) void k4a_vab(
    const float* __restrict__ Wp2, const float* __restrict__ as2,
    const float* __restrict__ at2, float* __restrict__ va, float* __restrict__ vb)
{
  const int lane = threadIdx.x & 63;
  const int w = threadIdx.x >> 6;
  const int r = blockIdx.x * 4 + w;
  const float4 wv = *(const float4*)(Wp2 + (size_t)r * DD2 + lane * 4);
  const float4 a = *(const float4*)(as2 + lane * 4);
  const float4 b = *(const float4*)(at2 + lane * 4);
  float ps = wv.x * a.x + wv.y * a.y + wv.z * a.z + wv.w * a.w;
  float pt = wv.x * b.x + wv.y * b.y + wv.z * b.z + wv.w * b.w;
#pragma unroll
  for (int off = 32; off > 0; off >>= 1) {
    ps += __shfl_down(ps, off);
    pt += __shfl_down(pt, off);
  }
  if (lane == 0) { va[r] = ps; vb[r] = pt; }
}

// ---------------------------------------------------------------- k4b
// ss[n] = out_elu[n]·va, st[n] = out_elu[n]·vb. grid 1024, wave per row.
__global__ __launch_bounds__(256) void k4b_sst(
    const float* __restrict__ oe, const float* __restrict__ va,
    const float* __restrict__ vb, float* __restrict__ ss, float* __restrict__ st)
{
  const int lane = threadIdx.x & 63;
  const int w = threadIdx.x >> 6;
  const int r = blockIdx.x * 4 + w;
  const float4 ov = *(const float4*)(oe + (size_t)r * DD2 + lane * 4);
  const float4 a = *(const float4*)(va + lane * 4);
  const float4 b = *(const float4*)(vb + lane * 4);
  float ps = ov.x * a.x + ov.y * a.y + ov.z * a.z + ov.w * a.w;
  float pt = ov.x * b.x + ov.y * b.y + ov.z * b.z + ov.w * b.w;
#pragma unroll
  for (int off = 32; off > 0; off >>= 1) {
    ps += __shfl_down(ps, off);
    pt += __shfl_down(pt, off);
  }
  if (lane == 0) { ss[r] = ps; st[r] = pt; }
}

// ---------------------------------------------------------------- k5
// msw = relu(ss_i + st_j) * sw. grid 16384, float4 per thread.
// (round-0-verified code, untouched; overwrites the k2 bitmask scratch)
__global__ __launch_bounds__(256) void k5_msw(
    const float* __restrict__ ss, const float* __restrict__ st,
    const float* __restrict__ sw, float* __restrict__ msw)
{
  const size_t gid = (size_t)blockIdx.x * 256 + threadIdx.x;
  const int i = (int)(gid >> 10);
  const int j = (int)(gid & 1023) * 4;
  const float s = ss[i];
  const float4 tv = *(const float4*)(st + j);
  const float4 wv = *(const float4*)(sw + (size_t)i * NN + j);
  float4 r;
  r.x = fmaxf(s + tv.x, 0.f) * wv.x;
  r.y = fmaxf(s + tv.y, 0.f) * wv.y;
  r.z = fmaxf(s + tv.z, 0.f) * wv.z;
  r.w = fmaxf(s + tv.w, 0.f) * wv.w;
  *(float4*)(msw + (size_t)i * NN + j) = r;
}

// ---------------------------------------------------------------- k6m
// tmp1 = msw @ W1 on the matrix pipe. M=4096 N=96 K=4096.
// grid 2048 = 256 row-stripes x 8 k-splits; block 256 = 4 waves, wave covers
// 16 rows x 128 k. A-frags: msw fp32 loads + f2bf (m=lane&15 row, k=q*8+u).
// B-frags: W1T bf16 (same map as verified k3: B[k=q*8+u][col=m] at row m+n*16).
// C-frags: col=m, row=q*4+g. Cross-wave LDS reduce, 8-way atomicAdd.
__global__ __launch_bounds__(256) void k6m_mfma(
    const float* __restrict__ msw, const short* __restrict__ w1t,
    float* __restrict__ tmp1)
{
  __shared__ float red[4][16][NH1];   // 24 KB
  const int t = threadIdx.x;
  const int w = t >> 6;
  const int lane = t & 63;
  const int m = lane & 15;
  const int q = lane >> 4;
  const int i0 = (blockIdx.x >> 3) * 16;
  const int ja = (blockIdx.x & 7) * 512 + w * 128;

  const float* arow = msw + (size_t)(i0 + m) * NN;
  const short* bbase = w1t + (size_t)m * NN;   // col c = n*16+m lives at +n*16*NN

  f32x4 acc[6];
#pragma unroll
  for (int n = 0; n < 6; ++n) acc[n] = {0.f, 0.f, 0.f, 0.f};

  for (int jt = ja; jt < ja + 128; jt += 32) {
    const int j8 = jt + q * 8;
    const float4 a0 = *(const float4*)(arow + j8);
    const float4 a1 = *(const float4*)(arow + j8 + 4);
    bf16x8 af;
    af[0] = f2bf(a0.x); af[1] = f2bf(a0.y); af[2] = f2bf(a0.z); af[3] = f2bf(a0.w);
    af[4] = f2bf(a1.x); af[5] = f2bf(a1.y); af[6] = f2bf(a1.z); af[7] = f2bf(a1.w);
#pragma unroll
    for (int n = 0; n < 6; ++n) {
      const bf16x8 bf = *(const bf16x8*)(bbase + (size_t)n * 16 * NN + j8);
      acc[n] = __builtin_amdgcn_mfma_f32_16x16x32_bf16(af, bf, acc[n], 0, 0, 0);
    }
  }

  // partials -> LDS (C layout: col = lane&15, row = q*4+g)
#pragma unroll
  for (int n = 0; n < 6; ++n)
#pragma unroll
    for (int g = 0; g < 4; ++g)
      red[w][q * 4 + g][n * 16 + m] = acc[n][g];
  __syncthreads();

  for (int e = t; e < 16 * NH1; e += 256) {
    const int r = e / NH1, c = e - r * NH1;
    const float s = red[0][r][c] + red[1][r][c] + red[2][r][c] + red[3][r][c];
    atomicAdd(&tmp1[(size_t)(i0 + r) * NH1 + c], s);
  }
}

// ---------------------------------------------------------------- k7
// beta/y_hat head. grid 512 (8 rows/block), block 256.
__global__ __launch_bounds__(256) void k7_head(
    const float* __restrict__ tmp1, const float* __restrict__ b1,
    const float* __restrict__ W2, const float* __restrict__ b2,
    const float* __restrict__ W3, const float* __restrict__ b3,
    const float* __restrict__ ols, const float* __restrict__ vx,
    float* __restrict__ beta, float* __restrict__ yhat)
{
  __shared__ float w2s[96][32];
  __shared__ float w3s[32][16];
  __shared__ float t1s[8][96];
  __shared__ float t2s[8][33];
  const int t = threadIdx.x;
  const int r0 = blockIdx.x * 8;
  for (int i = t; i < 96 * 32; i += 256) w2s[i >> 5][i & 31] = W2[i];
  for (int i = t; i < 32 * 16; i += 256) w3s[i >> 4][i & 15] = W3[i];
  for (int i = t; i < 8 * 96; i += 256) {
    const int rr = i / 96, k = i - rr * 96;
    t1s[rr][k] = tmp1[(size_t)(r0 + rr) * 96 + k] + b1[k];
  }
  __syncthreads();
  {
    const int rr = t >> 5, c2 = t & 31;
    float a = b2[c2];
    for (int k = 0; k < 96; ++k) a += t1s[rr][k] * w2s[k][c2];
    t2s[rr][c2] = a;
  }
  __syncthreads();
  const int rr = t >> 5;
  const int v = t & 31;
  if (v < 16) {
    float z = b3[v];
#pragma unroll
    for (int k = 0; k < 32; ++k) z += t2s[rr][k] * w3s[k][v];
    z = fmaxf(z, 0.2f * z);               // leaky_relu(0.2)
    const float bvv = z * ols[v];
    const int r = r0 + rr;
    beta[(size_t)r * 16 + v] = bvv;
    float yv = bvv * vx[(size_t)r * 16 + v];
    yv += __shfl_down(yv, 8);
    yv += __shfl_down(yv, 4);
    yv += __shfl_down(yv, 2);
    yv += __shfl_down(yv, 1);
    if (v == 0) yhat[r] = yv;
  }
}

// ---------------------------------------------------------------- launch
// ws layout (bytes)
#define OFF_PT    0u
#define OFF_SKIPB 2097152u    // skipb (4MB); w1t (768KB) reuses this after k4b
#define OFF_SSRC  6291456u
#define OFF_STGT  6356992u
#define OFF_VA    6422528u
#define OFF_VB    6423552u
#define OFF_SS    6424576u
#define OFF_ST    6440960u
#define OFF_TMP1  6457344u
// d_out layout (floats)
#define OUT_YHAT 65536
#define OUT_MSW  69632

extern "C" void kernel_launch(void* const* d_in, const int* in_sizes, int n_in,
                              void* d_out, int out_size, void* d_ws, size_t ws_size,
                              hipStream_t stream) {
  const float* x    = (const float*)d_in[0];
  // d_in[1] edge_distances: unused by the reference
  const float* sw   = (const float*)d_in[2];
  const float* Wp1  = (const float*)d_in[3];
  const float* as1  = (const float*)d_in[4];
  const float* at1  = (const float*)d_in[5];
  const float* Wsk  = (const float*)d_in[6];
  const float* bias1= (const float*)d_in[7];
  const float* Wp2  = (const float*)d_in[8];
  const float* as2  = (const float*)d_in[9];
  const float* at2  = (const float*)d_in[10];
  const float* W1   = (const float*)d_in[11];
  const float* b1   = (const float*)d_in[12];
  const float* W2   = (const float*)d_in[13];
  const float* b2   = (const float*)d_in[14];
  const float* W3   = (const float*)d_in[15];
  const float* b3   = (const float*)d_in[16];
  const float* ols  = (const float*)d_in[17];
  const float* vx   = (const float*)d_in[18];

  float* out = (float*)d_out;
  char* ws = (char*)d_ws;
  short* pT    = (short*)(ws + OFF_PT);
  float* skipb = (float*)(ws + OFF_SKIPB);   // becomes out_elu in place (k3)
  short* w1t   = (short*)(ws + OFF_SKIPB);   // reuses skipb space (after k4b)
  float* s_src = (float*)(ws + OFF_SSRC);
  float* s_tgt = (float*)(ws + OFF_STGT);
  float* va    = (float*)(ws + OFF_VA);
  float* vb    = (float*)(ws + OFF_VB);
  float* ssv   = (float*)(ws + OFF_SS);
  float* stv   = (float*)(ws + OFF_ST);
  float* tmp1  = (float*)(ws + OFF_TMP1);
  unsigned* mask = (unsigned*)(out + OUT_MSW);  // 2MB scratch; k5 overwrites

  k1_proj<<<256, 256, 0, stream>>>(x, Wp1, Wsk, bias1, as1, at1, pT, skipb, s_src, s_tgt);
  k2_mask<<<2048, 256, 0, stream>>>(sw, mask);
  k3_attn<<<256, 1024, 0, stream>>>(pT, s_src, s_tgt, mask, skipb);
  k4a_vab<<<64, 256, 0, stream>>>(Wp2, as2, at2, va, vb);
  k4b_sst<<<1024, 256, 0, stream>>>(skipb, va, vb, ssv, stv);
  k0_w1t<<<64, 256, 0, stream>>>(W1, w1t);   // after k4b (clobbers skipb space)
  k5_msw<<<16384, 256, 0, stream>>>(ssv, stv, sw, out + OUT_MSW);
  hipMemsetAsync(tmp1, 0, (size_t)NN * NH1 * sizeof(float), stream);
  k6m_mfma<<<2048, 256, 0, stream>>>(out + OUT_MSW, w1t, tmp1);
  k7_head<<<512, 256, 0, stream>>>(tmp1, b1, W2, b2, W3, b3, ols, vx, out, out + OUT_YHAT);
}

// Round 7
// 319.907 us; speedup vs baseline: 1.3900x; 1.1557x over previous
//
#include <hip/hip_runtime.h>

// CatGWRegression on MI355X — fused GAT + GATW + regression head.
// Pipeline:
//  k1_proj : p = x@Wp1 (bf16, stored in MFMA-fragment-tiled layout pTf),
//            skipb = x@Wskip1+bias1, s_src/s_tgt row scores (pre-scaled by
//            log2(e) so k3 uses raw v_exp_f32).
//  k2_mask : maskT[jw][i] = bitmask(sw[i][jw*32..+32] > 0), transposed so k3's
//            mask load is one cache line (16 consecutive u32).
//  k3_attn : flash-style masked softmax attention. B-frag loads from pTf are
//            1KB fully-coalesced wave-loads (the old per-row layout scattered
//            16x64B per load -> CU vector-mem pipe serialized at ~6.5Kcyc/iter,
//            occupancy-invariant 87us). e-weights in A-frag layout; bf16 via
//            v_cvt_pk_bf16_f32; exp via exp2. 16 waves = 4 heads x 4 j-quarters,
//            LDS combine; epilogue normalize,+skip,elu -> skipb (out_elu).
//  k4a     : va = Wp2@a_src2, vb = Wp2@a_tgt2 (p2 eliminated by associativity)
//  k4b     : ss = out_elu@va, st = out_elu@vb
//  k0_w1t  : W1T[c][j] = bf16(W1[j][c]) into the skipb region (dead after k4b).
//  k5_msw  : msw = relu(ss_i+st_j)*sw -> d_out (overwrites mask scratch)
//  k6m     : tmp1 = msw @ W1 on the MATRIX pipe (verified round 4).
//  k7_head : beta = lrelu((tmp1+b1)@W2+b2)@W3+b3)*ols, y_hat = sum(beta*vx)

#define NN 4096
#define FF 128
#define DD2 256
#define NH1 96

typedef __attribute__((ext_vector_type(8))) short bf16x8;
typedef __attribute__((ext_vector_type(4))) float f32x4;

__device__ __forceinline__ short f2bf(float f) {
  unsigned u = __float_as_uint(f);
  u = u + 0x7FFFu + ((u >> 16) & 1u);   // RNE
  return (short)(u >> 16);
}

#define LOG2E 1.44269504088896340736f

// ---------------------------------------------------------------- k1
// grid 256, block 256. Block handles 16 rows x all 256 cols; K=128 streamed.
// pTf layout (bf16): element (h, sub, m; j) with jt32=j>>5, q=(j>>3)&3, e=j&7
//   at (h*128+jt32)*2048 + (sub*4+q)*128 + m*8 + e
// so k3's B-frag load for (h, tile, n) is pTf + (h*128+tile)*2048 + n*512 +
// lane*8 : 64 lanes x 16B contiguous = 1KB coalesced.
__global__ __launch_bounds__(256) void k1_proj(
    const float* __restrict__ x, const float* __restrict__ Wp1,
    const float* __restrict__ Wsk, const float* __restrict__ bias1,
    const float* __restrict__ as1, const float* __restrict__ at1,
    short* __restrict__ pTf, float* __restrict__ skipb,
    float* __restrict__ s_src, float* __restrict__ s_tgt)
{
  __shared__ float xs[16][FF];
  const int t = threadIdx.x;
  const int r0 = blockIdx.x * 16;
  for (int i = t; i < 16 * FF; i += 256)
    xs[i >> 7][i & 127] = x[(size_t)r0 * FF + i];
  __syncthreads();

  const int c = t;
  float accp[16], accs[16];
#pragma unroll
  for (int i = 0; i < 16; ++i) { accp[i] = 0.f; accs[i] = 0.f; }

  for (int k = 0; k < FF; k += 4) {
    float wp[4], wk[4];
#pragma unroll
    for (int u = 0; u < 4; ++u) {
      wp[u] = Wp1[(size_t)(k + u) * DD2 + c];
      wk[u] = Wsk[(size_t)(k + u) * DD2 + c];
    }
#pragma unroll
    for (int rr = 0; rr < 16; ++rr) {
      const float4 xv = *(const float4*)&xs[rr][k];  // uniform addr -> LDS broadcast
      accp[rr] += xv.x * wp[0] + xv.y * wp[1] + xv.z * wp[2] + xv.w * wp[3];
      accs[rr] += xv.x * wk[0] + xv.y * wk[1] + xv.z * wk[2] + xv.w * wk[3];
    }
  }

  const float asv = as1[t], atv = at1[t];  // a_src1[h][f], t = h*64+f
  const float bv = bias1[c];
  const int h = t >> 6;
  const int lane = t & 63;

#pragma unroll
  for (int rr = 0; rr < 16; ++rr)
    skipb[(size_t)(r0 + rr) * DD2 + c] = accs[rr] + bv;

  {  // pTf tiled-fragment stores: c = h*64 + sub*16 + mm; j = r0 + g*8 + e
    const int sub = (c >> 4) & 3;
    const int mm = c & 15;
    const int jt32 = r0 >> 5;
    const int qb = (r0 >> 3) & 3;        // r0 multiple of 16 -> 0 or 2
    short* base = pTf + (size_t)(h * 128 + jt32) * 2048 + (size_t)mm * 8;
#pragma unroll
    for (int g = 0; g < 2; ++g) {
      bf16x8 v;
#pragma unroll
      for (int e = 0; e < 8; ++e) v[e] = f2bf(accp[g * 8 + e]);
      *(bf16x8*)(base + (size_t)(sub * 4 + qb + g) * 128) = v;
    }
  }

#pragma unroll
  for (int rr = 0; rr < 16; ++rr) {  // s_src[h][i], s_tgt[h][i], pre-scaled
    float ps = accp[rr] * asv, pt = accp[rr] * atv;
#pragma unroll
    for (int off = 32; off > 0; off >>= 1) {
      ps += __shfl_down(ps, off);
      pt += __shfl_down(pt, off);
    }
    if (lane == 0) {
      s_src[h * NN + r0 + rr] = ps * LOG2E;
      s_tgt[h * NN + r0 + rr] = pt * LOG2E;
    }
  }
}

// ---------------------------------------------------------------- k2
// maskT[jw][i] = bitmask(sw[i][jw*32..+32] > 0). grid 2048, block 256.
// Reads identical to the verified version (coalesced float4 over j);
// store transposed (scattered 4B, ~1us total).
__global__ __launch_bounds__(256) void k2_mask(
    const float* __restrict__ sw, unsigned* __restrict__ maskT)
{
  const int g = blockIdx.x * 256 + threadIdx.x;
  const int i = g >> 7, jw = g & 127;
  const float* p = sw + (size_t)g * 32;   // = sw + i*NN + jw*32
  unsigned bits = 0;
#pragma unroll
  for (int u = 0; u < 8; ++u) {
    const float4 v = *(const float4*)(p + u * 4);
    const unsigned nib = (v.x > 0.f ? 1u : 0u) | (v.y > 0.f ? 2u : 0u)
                       | (v.z > 0.f ? 4u : 0u) | (v.w > 0.f ? 8u : 0u);
    bits |= nib << (u * 4);
  }
  maskT[(size_t)jw * NN + i] = bits;
}

// ---------------------------------------------------------------- k3
// grid 256, block 1024 = 16 waves: wave w handles head h=w&3, j-quarter qd=w>>2.
// All loads coalesced/broadcast (pTf 1KB wave-loads, maskT 1 line, s_tgt bcast).
// 1-deep prefetch; e = mask ? exp2(lrelu(scaled_s)) : 0; af via cvt_pk (RNE).
#define K3_STEP(T0, T1, MW, B0, B1, B2, B3) do {                               \
    const float tjv[8] = {T0.x, T0.y, T0.z, T0.w, T1.x, T1.y, T1.z, T1.w};     \
    const unsigned mb = (MW) >> (q * 8);                                       \
    float ev[8]; float esum = 0.f;                                             \
    _Pragma("unroll")                                                          \
    for (int u = 0; u < 8; ++u) {                                              \
      float s = ssrc + tjv[u];                                                 \
      s = fmaxf(s, 0.2f * s);                    /* leaky_relu(0.2) */         \
      const float e = ((mb >> u) & 1u) ? __builtin_amdgcn_exp2f(s) : 0.f;      \
      esum += e; ev[u] = e;                                                    \
    }                                                                          \
    lsum += esum;                                                              \
    union { unsigned u4[4]; bf16x8 v; } af_;                                   \
    _Pragma("unroll")                                                          \
    for (int pp = 0; pp < 4; ++pp)                                             \
      asm("v_cvt_pk_bf16_f32 %0, %1, %2"                                       \
          : "=v"(af_.u4[pp]) : "v"(ev[2 * pp]), "v"(ev[2 * pp + 1]));          \
    acc0 = __builtin_amdgcn_mfma_f32_16x16x32_bf16(af_.v, B0, acc0, 0, 0, 0);  \
    acc1 = __builtin_amdgcn_mfma_f32_16x16x32_bf16(af_.v, B1, acc1, 0, 0, 0);  \
    acc2 = __builtin_amdgcn_mfma_f32_16x16x32_bf16(af_.v, B2, acc2, 0, 0, 0);  \
    acc3 = __builtin_amdgcn_mfma_f32_16x16x32_bf16(af_.v, B3, acc3, 0, 0, 0);  \
  } while (0)

__global__ __launch_bounds__(1024) void k3_attn(
    const short* __restrict__ pTf, const float* __restrict__ s_src,
    const float* __restrict__ s_tgt, const unsigned* __restrict__ maskT,
    float* __restrict__ io /* in: skip+bias, out: elu(out) */)
{
  __shared__ float part[16][16][65];   // [wave][row][col-in-head], +1 pad
  __shared__ float lsum_s[16][16];     // [wave][row]
  const int t = threadIdx.x;
  const int lane = t & 63;
  const int w = t >> 6;     // 0..15
  const int h = w & 3;      // head
  const int qd = w >> 2;    // j-quarter
  const int m = lane & 15;
  const int q = lane >> 4;
  const int i0 = blockIdx.x * 16;

  const float ssrc = s_src[h * NN + i0 + m];
  const float* stg = s_tgt + h * NN;
  const unsigned* mcol = maskT + i0 + m;
  const short* pb = pTf + (size_t)h * 128 * 2048 + (size_t)lane * 8;

  f32x4 acc0 = {0.f, 0.f, 0.f, 0.f};
  f32x4 acc1 = acc0, acc2 = acc0, acc3 = acc0;
  float lsum = 0.f;

  const int jq = qd * 1024;
  {
    const int jb = jq + q * 8;
    const int tile0 = jq >> 5;
    float4 ct0 = *(const float4*)(stg + jb);
    float4 ct1 = *(const float4*)(stg + jb + 4);
    unsigned cmw = mcol[(size_t)tile0 * NN];
    const short* cp = pb + (size_t)tile0 * 2048;
    bf16x8 cb0 = *(const bf16x8*)(cp);
    bf16x8 cb1 = *(const bf16x8*)(cp + 512);
    bf16x8 cb2 = *(const bf16x8*)(cp + 1024);
    bf16x8 cb3 = *(const bf16x8*)(cp + 1536);

    for (int jt = jq; jt < jq + 1024 - 32; jt += 32) {
      const int ntile = (jt + 32) >> 5;
      const int njb = jt + 32 + q * 8;
      const float4 nt0 = *(const float4*)(stg + njb);
      const float4 nt1 = *(const float4*)(stg + njb + 4);
      const unsigned nmw = mcol[(size_t)ntile * NN];
      const short* np = pb + (size_t)ntile * 2048;
      const bf16x8 nb0 = *(const bf16x8*)(np);
      const bf16x8 nb1 = *(const bf16x8*)(np + 512);
      const bf16x8 nb2 = *(const bf16x8*)(np + 1024);
      const bf16x8 nb3 = *(const bf16x8*)(np + 1536);
      K3_STEP(ct0, ct1, cmw, cb0, cb1, cb2, cb3);
      ct0 = nt0; ct1 = nt1; cmw = nmw;
      cb0 = nb0; cb1 = nb1; cb2 = nb2; cb3 = nb3;
    }
    K3_STEP(ct0, ct1, cmw, cb0, cb1, cb2, cb3);
  }

  // per-wave l partial per row (xor over the 4 q-lanes of each row)
  lsum += __shfl_xor(lsum, 16);
  lsum += __shfl_xor(lsum, 32);
  if (q == 0) lsum_s[w][m] = lsum;

  // per-wave C partials -> LDS (C layout: col = lane&15, row = q*4+g)
  const f32x4 accs[4] = {acc0, acc1, acc2, acc3};
#pragma unroll
  for (int sub = 0; sub < 4; ++sub)
#pragma unroll
    for (int g = 0; g < 4; ++g)
      part[w][q * 4 + g][sub * 16 + m] = accs[sub][g];
  __syncthreads();

  // combine quarters + normalize + skip + elu. 16x256 elements / 1024 threads.
  for (int e = t; e < 16 * 256; e += 1024) {
    const int r = e >> 8;          // row in stripe
    const int c = e & 255;         // output column
    const int hh = c >> 6, cc = c & 63;
    float o = 0.f, l = 0.f;
#pragma unroll
    for (int qq = 0; qq < 4; ++qq) {
      o += part[qq * 4 + hh][r][cc];
      l += lsum_s[qq * 4 + hh][r];
    }
    float z = o / l + io[(size_t)(i0 + r) * DD2 + c];
    z = (z > 0.f) ? z : (__expf(z) - 1.f);   // elu
    io[(size_t)(i0 + r) * DD2 + c] = z;
  }
}

// ---------------------------------------------------------------- k0_w1t
// W1T[c][j] = bf16(W1[j][c]), 96 x 4096 bf16 (768 KB). grid 64, block 256.
// Tile-transpose via padded LDS. Output goes into the skipb region (dead after
// k4b); launched after k4b.
__global__ __launch_bounds__(256) void k0_w1t(
    const float* __restrict__ W1g, short* __restrict__ w1t)
{
  __shared__ short st[64 * 97];
  const int t = threadIdx.x;
  const int j0 = blockIdx.x * 64;
  for (int e = t; e < 64 * NH1; e += 256) {
    const int jj = e / NH1, c = e - jj * NH1;
    st[jj * 97 + c] = f2bf(W1g[(size_t)j0 * NH1 + e]);
  }
  __syncthreads();
  for (int o = t; o < NH1 * 32; o += 256) {      // packed pair writes
    const int c = o >> 5, jj2 = (o & 31) * 2;
    unsigned lo = (unsigned short)st[jj2 * 97 + c];
    unsigned hi = (unsigned short)st[(jj2 + 1) * 97 + c];
    *(unsigned*)(w1t + (size_t)c * NN + j0 + jj2) = lo | (hi << 16);
  }
}

// ---------------------------------------------------------------- k4a
// va = Wp2 @ a_src2, vb = Wp2 @ a_tgt2. grid 64, block 256 (wave per row).
__global__ __launch_bounds__(256) void k4a_vab(
    const float* __restrict__ Wp2, const float* __restrict__ as2,
    const float* __restrict__ at2, float* __restrict__ va, float* __restrict__ vb)
{
  const int lane = threadIdx.x & 63;
  const int w = threadIdx.x >> 6;
  const int r = blockIdx.x * 4 + w;
  const float4 wv = *(const float4*)(Wp2 + (size_t)r * DD2 + lane * 4);
  const float4 a = *(const float4*)(as2 + lane * 4);
  const float4 b = *(const float4*)(at2 + lane * 4);
  float ps = wv.x * a.x + wv.y * a.y + wv.z * a.z + wv.w * a.w;
  float pt = wv.x * b.x + wv.y * b.y + wv.z * b.z + wv.w * b.w;
#pragma unroll
  for (int off = 32; off > 0; off >>= 1) {
    ps += __shfl_down(ps, off);
    pt += __shfl_down(pt, off);
  }
  if (lane == 0) { va[r] = ps; vb[r] = pt; }
}

// ---------------------------------------------------------------- k4b
// ss[n] = out_elu[n]·va, st[n] = out_elu[n]·vb. grid 1024, wave per row.
__global__ __launch_bounds__(256) void k4b_sst(
    const float* __restrict__ oe, const float* __restrict__ va,
    const float* __restrict__ vb, float* __restrict__ ss, float* __restrict__ st)
{
  const int lane = threadIdx.x & 63;
  const int w = threadIdx.x >> 6;
  const int r = blockIdx.x * 4 + w;
  const float4 ov = *(const float4*)(oe + (size_t)r * DD2 + lane * 4);
  const float4 a = *(const float4*)(va + lane * 4);
  const float4 b = *(const float4*)(vb + lane * 4);
  float ps = ov.x * a.x + ov.y * a.y + ov.z * a.z + ov.w * a.w;
  float pt = ov.x * b.x + ov.y * b.y + ov.z * b.z + ov.w * b.w;
#pragma unroll
  for (int off = 32; off > 0; off >>= 1) {
    ps += __shfl_down(ps, off);
    pt += __shfl_down(pt, off);
  }
  if (lane == 0) { ss[r] = ps; st[r] = pt; }
}

// ---------------------------------------------------------------- k5
// msw = relu(ss_i + st_j) * sw. grid 16384, float4 per thread.
// (round-0-verified code, untouched; overwrites the k2 mask scratch)
__global__ __launch_bounds__(256) void k5_msw(
    const float* __restrict__ ss, const float* __restrict__ st,
    const float* __restrict__ sw, float* __restrict__ msw)
{
  const size_t gid = (size_t)blockIdx.x * 256 + threadIdx.x;
  const int i = (int)(gid >> 10);
  const int j = (int)(gid & 1023) * 4;
  const float s = ss[i];
  const float4 tv = *(const float4*)(st + j);
  const float4 wv = *(const float4*)(sw + (size_t)i * NN + j);
  float4 r;
  r.x = fmaxf(s + tv.x, 0.f) * wv.x;
  r.y = fmaxf(s + tv.y, 0.f) * wv.y;
  r.z = fmaxf(s + tv.z, 0.f) * wv.z;
  r.w = fmaxf(s + tv.w, 0.f) * wv.w;
  *(float4*)(msw + (size_t)i * NN + j) = r;
}

// ---------------------------------------------------------------- k6m
// tmp1 = msw @ W1 on the matrix pipe. M=4096 N=96 K=4096.
// grid 2048 = 256 row-stripes x 8 k-splits; block 256 = 4 waves, wave covers
// 16 rows x 128 k. A-frags: msw fp32 loads + f2bf (m=lane&15 row, k=q*8+u).
// B-frags: W1T bf16. C-frags: col=m, row=q*4+g. LDS reduce, 8-way atomicAdd.
__global__ __launch_bounds__(256) void k6m_mfma(
    const float* __restrict__ msw, const short* __restrict__ w1t,
    float* __restrict__ tmp1)
{
  __shared__ float red[4][16][NH1];   // 24 KB
  const int t = threadIdx.x;
  const int w = t >> 6;
  const int lane = t & 63;
  const int m = lane & 15;
  const int q = lane >> 4;
  const int i0 = (blockIdx.x >> 3) * 16;
  const int ja = (blockIdx.x & 7) * 512 + w * 128;

  const float* arow = msw + (size_t)(i0 + m) * NN;
  const short* bbase = w1t + (size_t)m * NN;   // col c = n*16+m lives at +n*16*NN

  f32x4 acc[6];
#pragma unroll
  for (int n = 0; n < 6; ++n) acc[n] = {0.f, 0.f, 0.f, 0.f};

  for (int jt = ja; jt < ja + 128; jt += 32) {
    const int j8 = jt + q * 8;
    const float4 a0 = *(const float4*)(arow + j8);
    const float4 a1 = *(const float4*)(arow + j8 + 4);
    bf16x8 af;
    af[0] = f2bf(a0.x); af[1] = f2bf(a0.y); af[2] = f2bf(a0.z); af[3] = f2bf(a0.w);
    af[4] = f2bf(a1.x); af[5] = f2bf(a1.y); af[6] = f2bf(a1.z); af[7] = f2bf(a1.w);
#pragma unroll
    for (int n = 0; n < 6; ++n) {
      const bf16x8 bf = *(const bf16x8*)(bbase + (size_t)n * 16 * NN + j8);
      acc[n] = __builtin_amdgcn_mfma_f32_16x16x32_bf16(af, bf, acc[n], 0, 0, 0);
    }
  }

  // partials -> LDS (C layout: col = lane&15, row = q*4+g)
#pragma unroll
  for (int n = 0; n < 6; ++n)
#pragma unroll
    for (int g = 0; g < 4; ++g)
      red[w][q * 4 + g][n * 16 + m] = acc[n][g];
  __syncthreads();

  for (int e = t; e < 16 * NH1; e += 256) {
    const int r = e / NH1, c = e - r * NH1;
    const float s = red[0][r][c] + red[1][r][c] + red[2][r][c] + red[3][r][c];
    atomicAdd(&tmp1[(size_t)(i0 + r) * NH1 + c], s);
  }
}

// ---------------------------------------------------------------- k7
// beta/y_hat head. grid 512 (8 rows/block), block 256.
__global__ __launch_bounds__(256) void k7_head(
    const float* __restrict__ tmp1, const float* __restrict__ b1,
    const float* __restrict__ W2, const float* __restrict__ b2,
    const float* __restrict__ W3, const float* __restrict__ b3,
    const float* __restrict__ ols, const float* __restrict__ vx,
    float* __restrict__ beta, float* __restrict__ yhat)
{
  __shared__ float w2s[96][32];
  __shared__ float w3s[32][16];
  __shared__ float t1s[8][96];
  __shared__ float t2s[8][33];
  const int t = threadIdx.x;
  const int r0 = blockIdx.x * 8;
  for (int i = t; i < 96 * 32; i += 256) w2s[i >> 5][i & 31] = W2[i];
  for (int i = t; i < 32 * 16; i += 256) w3s[i >> 4][i & 15] = W3[i];
  for (int i = t; i < 8 * 96; i += 256) {
    const int rr = i / 96, k = i - rr * 96;
    t1s[rr][k] = tmp1[(size_t)(r0 + rr) * 96 + k] + b1[k];
  }
  __syncthreads();
  {
    const int rr = t >> 5, c2 = t & 31;
    float a = b2[c2];
    for (int k = 0; k < 96; ++k) a += t1s[rr][k] * w2s[k][c2];
    t2s[rr][c2] = a;
  }
  __syncthreads();
  const int rr = t >> 5;
  const int v = t & 31;
  if (v < 16) {
    float z = b3[v];
#pragma unroll
    for (int k = 0; k < 32; ++k) z += t2s[rr][k] * w3s[k][v];
    z = fmaxf(z, 0.2f * z);               // leaky_relu(0.2)
    const float bvv = z * ols[v];
    const int r = r0 + rr;
    beta[(size_t)r * 16 + v] = bvv;
    float yv = bvv * vx[(size_t)r * 16 + v];
    yv += __shfl_down(yv, 8);
    yv += __shfl_down(yv, 4);
    yv += __shfl_down(yv, 2);
    yv += __shfl_down(yv, 1);
    if (v == 0) yhat[r] = yv;
  }
}

// ---------------------------------------------------------------- launch
// ws layout (bytes)
#define OFF_PT    0u
#define OFF_SKIPB 2097152u    // skipb (4MB); w1t (768KB) reuses this after k4b
#define OFF_SSRC  6291456u
#define OFF_STGT  6356992u
#define OFF_VA    6422528u
#define OFF_VB    6423552u
#define OFF_SS    6424576u
#define OFF_ST    6440960u
#define OFF_TMP1  6457344u
// d_out layout (floats)
#define OUT_YHAT 65536
#define OUT_MSW  69632

extern "C" void kernel_launch(void* const* d_in, const int* in_sizes, int n_in,
                              void* d_out, int out_size, void* d_ws, size_t ws_size,
                              hipStream_t stream) {
  const float* x    = (const float*)d_in[0];
  // d_in[1] edge_distances: unused by the reference
  const float* sw   = (const float*)d_in[2];
  const float* Wp1  = (const float*)d_in[3];
  const float* as1  = (const float*)d_in[4];
  const float* at1  = (const float*)d_in[5];
  const float* Wsk  = (const float*)d_in[6];
  const float* bias1= (const float*)d_in[7];
  const float* Wp2  = (const float*)d_in[8];
  const float* as2  = (const float*)d_in[9];
  const float* at2  = (const float*)d_in[10];
  const float* W1   = (const float*)d_in[11];
  const float* b1   = (const float*)d_in[12];
  const float* W2   = (const float*)d_in[13];
  const float* b2   = (const float*)d_in[14];
  const float* W3   = (const float*)d_in[15];
  const float* b3   = (const float*)d_in[16];
  const float* ols  = (const float*)d_in[17];
  const float* vx   = (const float*)d_in[18];

  float* out = (float*)d_out;
  char* ws = (char*)d_ws;
  short* pTf   = (short*)(ws + OFF_PT);
  float* skipb = (float*)(ws + OFF_SKIPB);   // becomes out_elu in place (k3)
  short* w1t   = (short*)(ws + OFF_SKIPB);   // reuses skipb space (after k4b)
  float* s_src = (float*)(ws + OFF_SSRC);
  float* s_tgt = (float*)(ws + OFF_STGT);
  float* va    = (float*)(ws + OFF_VA);
  float* vb    = (float*)(ws + OFF_VB);
  float* ssv   = (float*)(ws + OFF_SS);
  float* stv   = (float*)(ws + OFF_ST);
  float* tmp1  = (float*)(ws + OFF_TMP1);
  unsigned* maskT = (unsigned*)(out + OUT_MSW);  // 2MB scratch; k5 overwrites

  k1_proj<<<256, 256, 0, stream>>>(x, Wp1, Wsk, bias1, as1, at1, pTf, skipb, s_src, s_tgt);
  k2_mask<<<2048, 256, 0, stream>>>(sw, maskT);
  k3_attn<<<256, 1024, 0, stream>>>(pTf, s_src, s_tgt, maskT, skipb);
  k4a_vab<<<64, 256, 0, stream>>>(Wp2, as2, at2, va, vb);
  k4b_sst<<<1024, 256, 0, stream>>>(skipb, va, vb, ssv, stv);
  k0_w1t<<<64, 256, 0, stream>>>(W1, w1t);   // after k4b (clobbers skipb space)
  k5_msw<<<16384, 256, 0, stream>>>(ssv, stv, sw, out + OUT_MSW);
  hipMemsetAsync(tmp1, 0, (size_t)NN * NH1 * sizeof(float), stream);
  k6m_mfma<<<2048, 256, 0, stream>>>(out + OUT_MSW, w1t, tmp1);
  k7_head<<<512, 256, 0, stream>>>(tmp1, b1, W2, b2, W3, b3, ols, vx, out, out + OUT_YHAT);
}

// Round 8
// 293.738 us; speedup vs baseline: 1.5138x; 1.0891x over previous
//
#include <hip/hip_runtime.h>

// CatGWRegression on MI355X — fused GAT + GATW + regression head.
// Pipeline:
//  k1_proj : p = x@Wp1 (bf16, stored in MFMA-fragment-tiled layout pTf),
//            skipb = x@Wskip1+bias1, s_src/s_tgt row scores (pre-scaled by
//            log2(e) so k3 uses raw v_exp_f32).
//  k2_mask : maskT[jw][i] = bitmask(sw[i][jw*32..+32] > 0) + zeroes tmp1
//            (folds the old hipMemsetAsync dispatch).
//  k3_attn : flash-style masked softmax attention; pTf B-frags are 1KB coalesced
//            wave-loads (round-7 fix, -50us). 16 waves = 4 heads x 4 j-quarters,
//            LDS combine; epilogue normalize,+skip,elu -> skipb (out_elu).
//  k0_w1t  : W1 -> fragment-tiled bf16 w1tf (same layout trick as pTf) into the
//            pT region (dead after k3).
//  k4a     : va = Wp2@a_src2, vb = Wp2@a_tgt2 (p2 eliminated by associativity)
//  k4b     : ss = out_elu@va, st = out_elu@vb
//  k56     : FUSED k5+k6m. Phase 1: v = relu(ss_i+st_j)*sw with k5's exact
//            coalesced float4 pattern -> msw (d_out) + bf16 A-tile in LDS.
//            Phase 2: k6m's MFMA (A from LDS, B = w1tf coalesced). Phase 3:
//            k6m's LDS reduce + 8-way atomicAdd. Saves k5's separate 64MB msw
//            read-back + 2 launches. LDS union 24KB.
//  k7_head : beta = lrelu((tmp1+b1)@W2+b2)@W3+b3)*ols, y_hat = sum(beta*vx)

#define NN 4096
#define FF 128
#define DD2 256
#define NH1 96

typedef __attribute__((ext_vector_type(8))) short bf16x8;
typedef __attribute__((ext_vector_type(4))) float f32x4;

__device__ __forceinline__ short f2bf(float f) {
  unsigned u = __float_as_uint(f);
  u = u + 0x7FFFu + ((u >> 16) & 1u);   // RNE
  return (short)(u >> 16);
}

#define LOG2E 1.44269504088896340736f

// ---------------------------------------------------------------- k1
// grid 256, block 256. Block handles 16 rows x all 256 cols; K=128 streamed.
// pTf layout (bf16): element (h, n, m; j) with jt32=j>>5, q=(j>>3)&3, e=j&7
//   at (h*128+jt32)*2048 + n*512 + q*128 + m*8 + e
// so k3's B-frag load for (h, tile, n) is pTf + (h*128+tile)*2048 + n*512 +
// lane*8 : 64 lanes x 16B contiguous = 1KB coalesced.
__global__ __launch_bounds__(256) void k1_proj(
    const float* __restrict__ x, const float* __restrict__ Wp1,
    const float* __restrict__ Wsk, const float* __restrict__ bias1,
    const float* __restrict__ as1, const float* __restrict__ at1,
    short* __restrict__ pTf, float* __restrict__ skipb,
    float* __restrict__ s_src, float* __restrict__ s_tgt)
{
  __shared__ float xs[16][FF];
  const int t = threadIdx.x;
  const int r0 = blockIdx.x * 16;
  for (int i = t; i < 16 * FF; i += 256)
    xs[i >> 7][i & 127] = x[(size_t)r0 * FF + i];
  __syncthreads();

  const int c = t;
  float accp[16], accs[16];
#pragma unroll
  for (int i = 0; i < 16; ++i) { accp[i] = 0.f; accs[i] = 0.f; }

  for (int k = 0; k < FF; k += 4) {
    float wp[4], wk[4];
#pragma unroll
    for (int u = 0; u < 4; ++u) {
      wp[u] = Wp1[(size_t)(k + u) * DD2 + c];
      wk[u] = Wsk[(size_t)(k + u) * DD2 + c];
    }
#pragma unroll
    for (int rr = 0; rr < 16; ++rr) {
      const float4 xv = *(const float4*)&xs[rr][k];  // uniform addr -> LDS broadcast
      accp[rr] += xv.x * wp[0] + xv.y * wp[1] + xv.z * wp[2] + xv.w * wp[3];
      accs[rr] += xv.x * wk[0] + xv.y * wk[1] + xv.z * wk[2] + xv.w * wk[3];
    }
  }

  const float asv = as1[t], atv = at1[t];  // a_src1[h][f], t = h*64+f
  const float bv = bias1[c];
  const int h = t >> 6;
  const int lane = t & 63;

#pragma unroll
  for (int rr = 0; rr < 16; ++rr)
    skipb[(size_t)(r0 + rr) * DD2 + c] = accs[rr] + bv;

  {  // pTf tiled-fragment stores: c = h*64 + sub*16 + mm; j = r0 + g*8 + e
    const int sub = (c >> 4) & 3;
    const int mm = c & 15;
    const int jt32 = r0 >> 5;
    const int qb = (r0 >> 3) & 3;        // r0 multiple of 16 -> 0 or 2
    short* base = pTf + (size_t)(h * 128 + jt32) * 2048 + (size_t)mm * 8;
#pragma unroll
    for (int g = 0; g < 2; ++g) {
      bf16x8 v;
#pragma unroll
      for (int e = 0; e < 8; ++e) v[e] = f2bf(accp[g * 8 + e]);
      *(bf16x8*)(base + (size_t)(sub * 4 + qb + g) * 128) = v;
    }
  }

#pragma unroll
  for (int rr = 0; rr < 16; ++rr) {  // s_src[h][i], s_tgt[h][i], pre-scaled
    float ps = accp[rr] * asv, pt = accp[rr] * atv;
#pragma unroll
    for (int off = 32; off > 0; off >>= 1) {
      ps += __shfl_down(ps, off);
      pt += __shfl_down(pt, off);
    }
    if (lane == 0) {
      s_src[h * NN + r0 + rr] = ps * LOG2E;
      s_tgt[h * NN + r0 + rr] = pt * LOG2E;
    }
  }
}

// ---------------------------------------------------------------- k2
// maskT[jw][i] = bitmask(sw[i][jw*32..+32] > 0). grid 2048, block 256.
// Also zeroes tmp1 (g < NN*NH1) for k56's atomicAdd accumulation.
__global__ __launch_bounds__(256) void k2_mask(
    const float* __restrict__ sw, unsigned* __restrict__ maskT,
    float* __restrict__ tmp1)
{
  const int g = blockIdx.x * 256 + threadIdx.x;
  const int i = g >> 7, jw = g & 127;
  const float* p = sw + (size_t)g * 32;   // = sw + i*NN + jw*32
  unsigned bits = 0;
#pragma unroll
  for (int u = 0; u < 8; ++u) {
    const float4 v = *(const float4*)(p + u * 4);
    const unsigned nib = (v.x > 0.f ? 1u : 0u) | (v.y > 0.f ? 2u : 0u)
                       | (v.z > 0.f ? 4u : 0u) | (v.w > 0.f ? 8u : 0u);
    bits |= nib << (u * 4);
  }
  maskT[(size_t)jw * NN + i] = bits;
  if (g < NN * NH1) tmp1[g] = 0.f;
}

// ---------------------------------------------------------------- k3
// grid 256, block 1024 = 16 waves: wave w handles head h=w&3, j-quarter qd=w>>2.
// All loads coalesced/broadcast (pTf 1KB wave-loads, maskT 1 line, s_tgt bcast).
// 1-deep prefetch; e = mask ? exp2(lrelu(scaled_s)) : 0; af via cvt_pk (RNE).
#define K3_STEP(T0, T1, MW, B0, B1, B2, B3) do {                               \
    const float tjv[8] = {T0.x, T0.y, T0.z, T0.w, T1.x, T1.y, T1.z, T1.w};     \
    const unsigned mb = (MW) >> (q * 8);                                       \
    float ev[8]; float esum = 0.f;                                             \
    _Pragma("unroll")                                                          \
    for (int u = 0; u < 8; ++u) {                                              \
      float s = ssrc + tjv[u];                                                 \
      s = fmaxf(s, 0.2f * s);                    /* leaky_relu(0.2) */         \
      const float e = ((mb >> u) & 1u) ? __builtin_amdgcn_exp2f(s) : 0.f;      \
      esum += e; ev[u] = e;                                                    \
    }                                                                          \
    lsum += esum;                                                              \
    union { unsigned u4[4]; bf16x8 v; } af_;                                   \
    _Pragma("unroll")                                                          \
    for (int pp = 0; pp < 4; ++pp)                                             \
      asm("v_cvt_pk_bf16_f32 %0, %1, %2"                                       \
          : "=v"(af_.u4[pp]) : "v"(ev[2 * pp]), "v"(ev[2 * pp + 1]));          \
    acc0 = __builtin_amdgcn_mfma_f32_16x16x32_bf16(af_.v, B0, acc0, 0, 0, 0);  \
    acc1 = __builtin_amdgcn_mfma_f32_16x16x32_bf16(af_.v, B1, acc1, 0, 0, 0);  \
    acc2 = __builtin_amdgcn_mfma_f32_16x16x32_bf16(af_.v, B2, acc2, 0, 0, 0);  \
    acc3 = __builtin_amdgcn_mfma_f32_16x16x32_bf16(af_.v, B3, acc3, 0, 0, 0);  \
  } while (0)

__global__ __launch_bounds__(1024) void k3_attn(
    const short* __restrict__ pTf, const float* __restrict__ s_src,
    const float* __restrict__ s_tgt, const unsigned* __restrict__ maskT,
    float* __restrict__ io /* in: skip+bias, out: elu(out) */)
{
  __shared__ float part[16][16][65];   // [wave][row][col-in-head], +1 pad
  __shared__ float lsum_s[16][16];     // [wave][row]
  const int t = threadIdx.x;
  const int lane = t & 63;
  const int w = t >> 6;     // 0..15
  const int h = w & 3;      // head
  const int qd = w >> 2;    // j-quarter
  const int m = lane & 15;
  const int q = lane >> 4;
  const int i0 = blockIdx.x * 16;

  const float ssrc = s_src[h * NN + i0 + m];
  const float* stg = s_tgt + h * NN;
  const unsigned* mcol = maskT + i0 + m;
  const short* pb = pTf + (size_t)h * 128 * 2048 + (size_t)lane * 8;

  f32x4 acc0 = {0.f, 0.f, 0.f, 0.f};
  f32x4 acc1 = acc0, acc2 = acc0, acc3 = acc0;
  float lsum = 0.f;

  const int jq = qd * 1024;
  {
    const int jb = jq + q * 8;
    const int tile0 = jq >> 5;
    float4 ct0 = *(const float4*)(stg + jb);
    float4 ct1 = *(const float4*)(stg + jb + 4);
    unsigned cmw = mcol[(size_t)tile0 * NN];
    const short* cp = pb + (size_t)tile0 * 2048;
    bf16x8 cb0 = *(const bf16x8*)(cp);
    bf16x8 cb1 = *(const bf16x8*)(cp + 512);
    bf16x8 cb2 = *(const bf16x8*)(cp + 1024);
    bf16x8 cb3 = *(const bf16x8*)(cp + 1536);

    for (int jt = jq; jt < jq + 1024 - 32; jt += 32) {
      const int ntile = (jt + 32) >> 5;
      const int njb = jt + 32 + q * 8;
      const float4 nt0 = *(const float4*)(stg + njb);
      const float4 nt1 = *(const float4*)(stg + njb + 4);
      const unsigned nmw = mcol[(size_t)ntile * NN];
      const short* np = pb + (size_t)ntile * 2048;
      const bf16x8 nb0 = *(const bf16x8*)(np);
      const bf16x8 nb1 = *(const bf16x8*)(np + 512);
      const bf16x8 nb2 = *(const bf16x8*)(np + 1024);
      const bf16x8 nb3 = *(const bf16x8*)(np + 1536);
      K3_STEP(ct0, ct1, cmw, cb0, cb1, cb2, cb3);
      ct0 = nt0; ct1 = nt1; cmw = nmw;
      cb0 = nb0; cb1 = nb1; cb2 = nb2; cb3 = nb3;
    }
    K3_STEP(ct0, ct1, cmw, cb0, cb1, cb2, cb3);
  }

  // per-wave l partial per row (xor over the 4 q-lanes of each row)
  lsum += __shfl_xor(lsum, 16);
  lsum += __shfl_xor(lsum, 32);
  if (q == 0) lsum_s[w][m] = lsum;

  // per-wave C partials -> LDS (C layout: col = lane&15, row = q*4+g)
  const f32x4 accs[4] = {acc0, acc1, acc2, acc3};
#pragma unroll
  for (int sub = 0; sub < 4; ++sub)
#pragma unroll
    for (int g = 0; g < 4; ++g)
      part[w][q * 4 + g][sub * 16 + m] = accs[sub][g];
  __syncthreads();

  // combine quarters + normalize + skip + elu. 16x256 elements / 1024 threads.
  for (int e = t; e < 16 * 256; e += 1024) {
    const int r = e >> 8;          // row in stripe
    const int c = e & 255;         // output column
    const int hh = c >> 6, cc = c & 63;
    float o = 0.f, l = 0.f;
#pragma unroll
    for (int qq = 0; qq < 4; ++qq) {
      o += part[qq * 4 + hh][r][cc];
      l += lsum_s[qq * 4 + hh][r];
    }
    float z = o / l + io[(size_t)(i0 + r) * DD2 + c];
    z = (z > 0.f) ? z : (__expf(z) - 1.f);   // elu
    io[(size_t)(i0 + r) * DD2 + c] = z;
  }
}

// ---------------------------------------------------------------- k0_w1t
// W1 -> fragment-tiled bf16 w1tf: element W1[j][c] with jt32=j>>5, q=(j>>3)&3,
// e=j&7, n=c>>4, m=c&15 at jt32*3072 + n*512 + (q*16+m)*8 + e, so k56's B-frag
// load (tile, n) = w1tf + tile*3072 + n*512 + lane*8 is a 1KB coalesced
// wave-load. grid 64 (64 j-rows each), block 256; LDS-staged transpose.
// Output into the pT region (dead after k3); launched after k3.
__global__ __launch_bounds__(256) void k0_w1t(
    const float* __restrict__ W1g, short* __restrict__ w1tf)
{
  __shared__ short stw[64 * 97];
  const int t = threadIdx.x;
  const int j0 = blockIdx.x * 64;
  for (int e = t; e < 64 * NH1; e += 256) {
    const int jj = e / NH1, c = e - jj * NH1;
    stw[jj * 97 + c] = f2bf(W1g[(size_t)(j0 + jj) * NH1 + c]);
  }
  __syncthreads();
  for (int o = t; o < 768; o += 256) {   // 768 = 2 tiles x 6 n x 4 q x 16 m
    const int m = o & 15;
    const int rest = o >> 4;             // (tile*6+n)*4+q
    const int q = rest & 3;
    const int tn = rest >> 2;
    const int tile = tn / 6, n = tn - tile * 6;
    bf16x8 v;
#pragma unroll
    for (int e8 = 0; e8 < 8; ++e8)
      v[e8] = stw[(tile * 32 + q * 8 + e8) * 97 + n * 16 + m];
    *(bf16x8*)(w1tf + (size_t)((j0 >> 5) + tile) * 3072 + n * 512
               + (size_t)(q * 16 + m) * 8) = v;
  }
}

// ---------------------------------------------------------------- k4a
// va = Wp2 @ a_src2, vb = Wp2 @ a_tgt2. grid 64, block 256 (wave per row).
__global__ __launch_bounds__(256) void k4a_vab(
    const float* __restrict__ Wp2, const float* __restrict__ as2,
    const float* __restrict__ at2, float* __restrict__ va, float* __restrict__ vb)
{
  const int lane = threadIdx.x & 63;
  const int w = threadIdx.x >> 6;
  const int r = blockIdx.x * 4 + w;
  const float4 wv = *(const float4*)(Wp2 + (size_t)r * DD2 + lane * 4);
  const float4 a = *(const float4*)(as2 + lane * 4);
  const float4 b = *(const float4*)(at2 + lane * 4);
  float ps = wv.x * a.x + wv.y * a.y + wv.z * a.z + wv.w * a.w;
  float pt = wv.x * b.x + wv.y * b.y + wv.z * b.z + wv.w * b.w;
#pragma unroll
  for (int off = 32; off > 0; off >>= 1) {
    ps += __shfl_down(ps, off);
    pt += __shfl_down(pt, off);
  }
  if (lane == 0) { va[r] = ps; vb[r] = pt; }
}

// ---------------------------------------------------------------- k4b
// ss[n] = out_elu[n]·va, st[n] = out_elu[n]·vb. grid 1024, wave per row.
__global__ __launch_bounds__(256) void k4b_sst(
    const float* __restrict__ oe, const float* __restrict__ va,
    const float* __restrict__ vb, float* __restrict__ ss, float* __restrict__ st)
{
  const int lane = threadIdx.x & 63;
  const int w = threadIdx.x >> 6;
  const int r = blockIdx.x * 4 + w;
  const float4 ov = *(const float4*)(oe + (size_t)r * DD2 + lane * 4);
  const float4 a = *(const float4*)(va + lane * 4);
  const float4 b = *(const float4*)(vb + lane * 4);
  float ps = ov.x * a.x + ov.y * a.y + ov.z * a.z + ov.w * a.w;
  float pt = ov.x * b.x + ov.y * b.y + ov.z * b.z + ov.w * b.w;
#pragma unroll
  for (int off = 32; off > 0; off >>= 1) {
    ps += __shfl_down(ps, off);
    pt += __shfl_down(pt, off);
  }
  if (lane == 0) { ss[r] = ps; st[r] = pt; }
}

// ---------------------------------------------------------------- k56
// FUSED k5+k6m: tmp1 = msw @ W1 with msw computed on the fly, M=4096 N=96
// K=4096. grid 2048 = 256 row-stripes x 8 k-splits; block 256 = 4 waves.
// Phase 1: k5's exact coalesced pattern computes v = relu(ss_i+st_j)*sw for
// the block's 16x512 tile -> msw (d_out, fp32) + bf16 A-tile in LDS (cvt_pk).
// Phase 2: k6m's MFMA loop verbatim; A-frags = 16B LDS reads (lane(m,q) ->
// sh.a[m][jloc+q*8], stride 520 shorts is bank-benign), B-frags = w1tf 1KB
// coalesced wave-loads. Phase 3: k6m's LDS reduce + 8-way atomicAdd.
__global__ __launch_bounds__(256) void k56_fused(
    const float* __restrict__ ss, const float* __restrict__ stv,
    const float* __restrict__ sw, const short* __restrict__ w1tf,
    float* __restrict__ msw, float* __restrict__ tmp1)
{
  __shared__ union {
    ushort a[16][520];           // bf16 A-tile (phase 1 -> 2), 16.6 KB
    float red[4][16][NH1];       // cross-wave reduce (phase 3), 24 KB
  } sh;
  const int t = threadIdx.x;
  const int w = t >> 6;
  const int lane = t & 63;
  const int m = lane & 15;
  const int q = lane >> 4;
  const int i0 = (blockIdx.x >> 3) * 16;
  const int j0 = (blockIdx.x & 7) * 512;

  // ---- phase 1: compute + write msw (coalesced) + stash bf16 A-tile
#pragma unroll
  for (int it = 0; it < 8; ++it) {
    const int idx = it * 256 + t;        // float4 slot in 16x512 tile
    const int row = idx >> 7;
    const int colf = idx & 127;
    const int j = j0 + colf * 4;
    const float ssv = ss[i0 + row];
    const float4 wv = *(const float4*)(sw + (size_t)(i0 + row) * NN + j);
    const float4 tv = *(const float4*)(stv + j);
    float4 v;
    v.x = fmaxf(ssv + tv.x, 0.f) * wv.x;
    v.y = fmaxf(ssv + tv.y, 0.f) * wv.y;
    v.z = fmaxf(ssv + tv.z, 0.f) * wv.z;
    v.w = fmaxf(ssv + tv.w, 0.f) * wv.w;
    *(float4*)(msw + (size_t)(i0 + row) * NN + j) = v;
    unsigned p0, p1;
    asm("v_cvt_pk_bf16_f32 %0, %1, %2" : "=v"(p0) : "v"(v.x), "v"(v.y));
    asm("v_cvt_pk_bf16_f32 %0, %1, %2" : "=v"(p1) : "v"(v.z), "v"(v.w));
    uint2 pk; pk.x = p0; pk.y = p1;
    *(uint2*)&sh.a[row][colf * 4] = pk;
  }
  __syncthreads();

  // ---- phase 2: MFMA (k6m structure). wave w covers local j [w*128, +128)
  f32x4 acc[6];
#pragma unroll
  for (int n = 0; n < 6; ++n) acc[n] = {0.f, 0.f, 0.f, 0.f};

#pragma unroll
  for (int kk = 0; kk < 128; kk += 32) {
    const int jloc = w * 128 + kk;
    const bf16x8 af = *(const bf16x8*)&sh.a[m][jloc + q * 8];
    const short* wt = w1tf + (size_t)((j0 + jloc) >> 5) * 3072 + (size_t)lane * 8;
#pragma unroll
    for (int n = 0; n < 6; ++n) {
      const bf16x8 bf = *(const bf16x8*)(wt + n * 512);
      acc[n] = __builtin_amdgcn_mfma_f32_16x16x32_bf16(af, bf, acc[n], 0, 0, 0);
    }
  }
  __syncthreads();   // all A-tile ds_reads done before union reuse

  // ---- phase 3: partials -> LDS (C layout: col = lane&15, row = q*4+g)
#pragma unroll
  for (int n = 0; n < 6; ++n)
#pragma unroll
    for (int g = 0; g < 4; ++g)
      sh.red[w][q * 4 + g][n * 16 + m] = acc[n][g];
  __syncthreads();

  for (int e = t; e < 16 * NH1; e += 256) {
    const int r = e / NH1, c = e - r * NH1;
    const float s = sh.red[0][r][c] + sh.red[1][r][c]
                  + sh.red[2][r][c] + sh.red[3][r][c];
    atomicAdd(&tmp1[(size_t)(i0 + r) * NH1 + c], s);
  }
}

// ---------------------------------------------------------------- k7
// beta/y_hat head. grid 512 (8 rows/block), block 256.
__global__ __launch_bounds__(256) void k7_head(
    const float* __restrict__ tmp1, const float* __restrict__ b1,
    const float* __restrict__ W2, const float* __restrict__ b2,
    const float* __restrict__ W3, const float* __restrict__ b3,
    const float* __restrict__ ols, const float* __restrict__ vx,
    float* __restrict__ beta, float* __restrict__ yhat)
{
  __shared__ float w2s[96][32];
  __shared__ float w3s[32][16];
  __shared__ float t1s[8][96];
  __shared__ float t2s[8][33];
  const int t = threadIdx.x;
  const int r0 = blockIdx.x * 8;
  for (int i = t; i < 96 * 32; i += 256) w2s[i >> 5][i & 31] = W2[i];
  for (int i = t; i < 32 * 16; i += 256) w3s[i >> 4][i & 15] = W3[i];
  for (int i = t; i < 8 * 96; i += 256) {
    const int rr = i / 96, k = i - rr * 96;
    t1s[rr][k] = tmp1[(size_t)(r0 + rr) * 96 + k] + b1[k];
  }
  __syncthreads();
  {
    const int rr = t >> 5, c2 = t & 31;
    float a = b2[c2];
    for (int k = 0; k < 96; ++k) a += t1s[rr][k] * w2s[k][c2];
    t2s[rr][c2] = a;
  }
  __syncthreads();
  const int rr = t >> 5;
  const int v = t & 31;
  if (v < 16) {
    float z = b3[v];
#pragma unroll
    for (int k = 0; k < 32; ++k) z += t2s[rr][k] * w3s[k][v];
    z = fmaxf(z, 0.2f * z);               // leaky_relu(0.2)
    const float bvv = z * ols[v];
    const int r = r0 + rr;
    beta[(size_t)r * 16 + v] = bvv;
    float yv = bvv * vx[(size_t)r * 16 + v];
    yv += __shfl_down(yv, 8);
    yv += __shfl_down(yv, 4);
    yv += __shfl_down(yv, 2);
    yv += __shfl_down(yv, 1);
    if (v == 0) yhat[r] = yv;
  }
}

// ---------------------------------------------------------------- launch
// ws layout (bytes)
#define OFF_PT    0u          // pTf (2MB); w1tf (768KB) reuses this after k3
#define OFF_SKIPB 2097152u
#define OFF_SSRC  6291456u
#define OFF_STGT  6356992u
#define OFF_VA    6422528u
#define OFF_VB    6423552u
#define OFF_SS    6424576u
#define OFF_ST    6440960u
#define OFF_TMP1  6457344u
// d_out layout (floats)
#define OUT_YHAT 65536
#define OUT_MSW  69632

extern "C" void kernel_launch(void* const* d_in, const int* in_sizes, int n_in,
                              void* d_out, int out_size, void* d_ws, size_t ws_size,
                              hipStream_t stream) {
  const float* x    = (const float*)d_in[0];
  // d_in[1] edge_distances: unused by the reference
  const float* sw   = (const float*)d_in[2];
  const float* Wp1  = (const float*)d_in[3];
  const float* as1  = (const float*)d_in[4];
  const float* at1  = (const float*)d_in[5];
  const float* Wsk  = (const float*)d_in[6];
  const float* bias1= (const float*)d_in[7];
  const float* Wp2  = (const float*)d_in[8];
  const float* as2  = (const float*)d_in[9];
  const float* at2  = (const float*)d_in[10];
  const float* W1   = (const float*)d_in[11];
  const float* b1   = (const float*)d_in[12];
  const float* W2   = (const float*)d_in[13];
  const float* b2   = (const float*)d_in[14];
  const float* W3   = (const float*)d_in[15];
  const float* b3   = (const float*)d_in[16];
  const float* ols  = (const float*)d_in[17];
  const float* vx   = (const float*)d_in[18];

  float* out = (float*)d_out;
  char* ws = (char*)d_ws;
  short* pTf   = (short*)(ws + OFF_PT);
  short* w1tf  = (short*)(ws + OFF_PT);      // reuses pTf space (after k3)
  float* skipb = (float*)(ws + OFF_SKIPB);   // becomes out_elu in place (k3)
  float* s_src = (float*)(ws + OFF_SSRC);
  float* s_tgt = (float*)(ws + OFF_STGT);
  float* va    = (float*)(ws + OFF_VA);
  float* vb    = (float*)(ws + OFF_VB);
  float* ssv   = (float*)(ws + OFF_SS);
  float* stv   = (float*)(ws + OFF_ST);
  float* tmp1  = (float*)(ws + OFF_TMP1);
  unsigned* maskT = (unsigned*)(out + OUT_MSW);  // 2MB scratch; k56 overwrites

  k1_proj<<<256, 256, 0, stream>>>(x, Wp1, Wsk, bias1, as1, at1, pTf, skipb, s_src, s_tgt);
  k2_mask<<<2048, 256, 0, stream>>>(sw, maskT, tmp1);
  k3_attn<<<256, 1024, 0, stream>>>(pTf, s_src, s_tgt, maskT, skipb);
  k0_w1t<<<64, 256, 0, stream>>>(W1, w1tf);  // after k3 (clobbers pTf space)
  k4a_vab<<<64, 256, 0, stream>>>(Wp2, as2, at2, va, vb);
  k4b_sst<<<1024, 256, 0, stream>>>(skipb, va, vb, ssv, stv);
  k56_fused<<<2048, 256, 0, stream>>>(ssv, stv, sw, w1tf, out + OUT_MSW, tmp1);
  k7_head<<<512, 256, 0, stream>>>(tmp1, b1, W2, b2, W3, b3, ols, vx, out, out + OUT_YHAT);
}

// Round 9
// 278.348 us; speedup vs baseline: 1.5975x; 1.0553x over previous
//
#include <hip/hip_runtime.h>

// CatGWRegression on MI355X — fused GAT + GATW + regression head.
// Pipeline:
//  k1_proj : p = x@Wp1 (bf16, stored in MFMA-fragment-tiled layout pTf),
//            skipb = x@Wskip1+bias1, s_src/s_tgt row scores (pre-scaled by
//            log2(e)). grid 1024 x 4 rows (was 256 x 16: 9.4% occupancy,
//            1 wave/SIMD -> latency-bound 40us).
//  k2_mask : maskT[jw][i] = bitmask(sw[i][jw*32..+32] > 0) + zeroes tmp1.
//  k3_attn : flash-style masked softmax attention; pTf B-frags are 1KB coalesced
//            wave-loads (round-7 fix). 16 waves = 4 heads x 4 j-quarters,
//            LDS combine; epilogue normalize,+skip,elu -> skipb (out_elu).
//  k0_w1t  : W1 -> fragment-tiled bf16 w1tf into the pT region (dead after k3).
//  k4a     : va = Wp2@a_src2, vb = Wp2@a_tgt2 (p2 eliminated by associativity)
//  k4b     : ss = out_elu@va, st = out_elu@vb
//  k56     : FUSED k5+k6m: msw computed (k5 formula, coalesced) -> d_out + LDS
//            bf16 A-tile; MFMA vs w1tf; LDS reduce + 8-way atomicAdd.
//  k7_head : beta = lrelu((tmp1+b1)@W2+b2)@W3+b3)*ols, y_hat = sum(beta*vx)

#define NN 4096
#define FF 128
#define DD2 256
#define NH1 96

typedef __attribute__((ext_vector_type(8))) short bf16x8;
typedef __attribute__((ext_vector_type(4))) float f32x4;

__device__ __forceinline__ short f2bf(float f) {
  unsigned u = __float_as_uint(f);
  u = u + 0x7FFFu + ((u >> 16) & 1u);   // RNE
  return (short)(u >> 16);
}

#define LOG2E 1.44269504088896340736f

// ---------------------------------------------------------------- k1
// grid 1024, block 256. Block handles 4 rows x all 256 cols; K=128 streamed.
// pTf layout (bf16): element (h, n, m; j) with jt32=j>>5, q=(j>>3)&3, e=j&7
//   at (h*128+jt32)*2048 + n*512 + q*128 + m*8 + e.
// A 4-row block (r0 4-aligned) writes e = (r0&7)..+3 of one j-group: jt32 and
// q are block-constant (4-aligned spans never straddle 8- or 32-boundaries),
// so the store is one 8B uint2 at the verified layout address.
__global__ __launch_bounds__(256) void k1_proj(
    const float* __restrict__ x, const float* __restrict__ Wp1,
    const float* __restrict__ Wsk, const float* __restrict__ bias1,
    const float* __restrict__ as1, const float* __restrict__ at1,
    short* __restrict__ pTf, float* __restrict__ skipb,
    float* __restrict__ s_src, float* __restrict__ s_tgt)
{
  __shared__ float xs[4][FF];
  const int t = threadIdx.x;
  const int r0 = blockIdx.x * 4;
  for (int i = t; i < 4 * FF; i += 256)
    xs[i >> 7][i & 127] = x[(size_t)r0 * FF + i];
  __syncthreads();

  const int c = t;
  float accp[4], accs[4];
#pragma unroll
  for (int i = 0; i < 4; ++i) { accp[i] = 0.f; accs[i] = 0.f; }

  for (int k = 0; k < FF; k += 4) {
    float wp[4], wk[4];
#pragma unroll
    for (int u = 0; u < 4; ++u) {
      wp[u] = Wp1[(size_t)(k + u) * DD2 + c];
      wk[u] = Wsk[(size_t)(k + u) * DD2 + c];
    }
#pragma unroll
    for (int rr = 0; rr < 4; ++rr) {
      const float4 xv = *(const float4*)&xs[rr][k];  // uniform addr -> LDS broadcast
      accp[rr] += xv.x * wp[0] + xv.y * wp[1] + xv.z * wp[2] + xv.w * wp[3];
      accs[rr] += xv.x * wk[0] + xv.y * wk[1] + xv.z * wk[2] + xv.w * wk[3];
    }
  }

  const float asv = as1[t], atv = at1[t];  // a_src1[h][f], t = h*64+f
  const float bv = bias1[c];
  const int h = t >> 6;
  const int lane = t & 63;

#pragma unroll
  for (int rr = 0; rr < 4; ++rr)
    skipb[(size_t)(r0 + rr) * DD2 + c] = accs[rr] + bv;

  {  // pTf tiled-fragment store: one uint2 (4 bf16) per thread
    const int sub = (c >> 4) & 3;
    const int mm = c & 15;
    const int jt32 = r0 >> 5;
    const int qb = (r0 >> 3) & 3;
    const int e0 = r0 & 7;               // 0 or 4
    unsigned p0, p1;
    asm("v_cvt_pk_bf16_f32 %0, %1, %2" : "=v"(p0) : "v"(accp[0]), "v"(accp[1]));
    asm("v_cvt_pk_bf16_f32 %0, %1, %2" : "=v"(p1) : "v"(accp[2]), "v"(accp[3]));
    uint2 pk; pk.x = p0; pk.y = p1;
    *(uint2*)(pTf + (size_t)(h * 128 + jt32) * 2048
              + (size_t)(sub * 4 + qb) * 128 + (size_t)mm * 8 + e0) = pk;
  }

#pragma unroll
  for (int rr = 0; rr < 4; ++rr) {  // s_src[h][i], s_tgt[h][i], pre-scaled
    float ps = accp[rr] * asv, pt = accp[rr] * atv;
#pragma unroll
    for (int off = 32; off > 0; off >>= 1) {
      ps += __shfl_down(ps, off);
      pt += __shfl_down(pt, off);
    }
    if (lane == 0) {
      s_src[h * NN + r0 + rr] = ps * LOG2E;
      s_tgt[h * NN + r0 + rr] = pt * LOG2E;
    }
  }
}

// ---------------------------------------------------------------- k2
// maskT[jw][i] = bitmask(sw[i][jw*32..+32] > 0). grid 2048, block 256.
// Also zeroes tmp1 (g < NN*NH1) for k56's atomicAdd accumulation.
__global__ __launch_bounds__(256) void k2_mask(
    const float* __restrict__ sw, unsigned* __restrict__ maskT,
    float* __restrict__ tmp1)
{
  const int g = blockIdx.x * 256 + threadIdx.x;
  const int i = g >> 7, jw = g & 127;
  const float* p = sw + (size_t)g * 32;   // = sw + i*NN + jw*32
  unsigned bits = 0;
#pragma unroll
  for (int u = 0; u < 8; ++u) {
    const float4 v = *(const float4*)(p + u * 4);
    const unsigned nib = (v.x > 0.f ? 1u : 0u) | (v.y > 0.f ? 2u : 0u)
                       | (v.z > 0.f ? 4u : 0u) | (v.w > 0.f ? 8u : 0u);
    bits |= nib << (u * 4);
  }
  maskT[(size_t)jw * NN + i] = bits;
  if (g < NN * NH1) tmp1[g] = 0.f;
}

// ---------------------------------------------------------------- k3
// grid 256, block 1024 = 16 waves: wave w handles head h=w&3, j-quarter qd=w>>2.
// All loads coalesced/broadcast (pTf 1KB wave-loads, maskT 1 line, s_tgt bcast).
// 1-deep prefetch; e = mask ? exp2(lrelu(scaled_s)) : 0; af via cvt_pk (RNE).
#define K3_STEP(T0, T1, MW, B0, B1, B2, B3) do {                               \
    const float tjv[8] = {T0.x, T0.y, T0.z, T0.w, T1.x, T1.y, T1.z, T1.w};     \
    const unsigned mb = (MW) >> (q * 8);                                       \
    float ev[8]; float esum = 0.f;                                             \
    _Pragma("unroll")                                                          \
    for (int u = 0; u < 8; ++u) {                                              \
      float s = ssrc + tjv[u];                                                 \
      s = fmaxf(s, 0.2f * s);                    /* leaky_relu(0.2) */         \
      const float e = ((mb >> u) & 1u) ? __builtin_amdgcn_exp2f(s) : 0.f;      \
      esum += e; ev[u] = e;                                                    \
    }                                                                          \
    lsum += esum;                                                              \
    union { unsigned u4[4]; bf16x8 v; } af_;                                   \
    _Pragma("unroll")                                                          \
    for (int pp = 0; pp < 4; ++pp)                                             \
      asm("v_cvt_pk_bf16_f32 %0, %1, %2"                                       \
          : "=v"(af_.u4[pp]) : "v"(ev[2 * pp]), "v"(ev[2 * pp + 1]));          \
    acc0 = __builtin_amdgcn_mfma_f32_16x16x32_bf16(af_.v, B0, acc0, 0, 0, 0);  \
    acc1 = __builtin_amdgcn_mfma_f32_16x16x32_bf16(af_.v, B1, acc1, 0, 0, 0);  \
    acc2 = __builtin_amdgcn_mfma_f32_16x16x32_bf16(af_.v, B2, acc2, 0, 0, 0);  \
    acc3 = __builtin_amdgcn_mfma_f32_16x16x32_bf16(af_.v, B3, acc3, 0, 0, 0);  \
  } while (0)

__global__ __launch_bounds__(1024) void k3_attn(
    const short* __restrict__ pTf, const float* __restrict__ s_src,
    const float* __restrict__ s_tgt, const unsigned* __restrict__ maskT,
    float* __restrict__ io /* in: skip+bias, out: elu(out) */)
{
  __shared__ float part[16][16][65];   // [wave][row][col-in-head], +1 pad
  __shared__ float lsum_s[16][16];     // [wave][row]
  const int t = threadIdx.x;
  const int lane = t & 63;
  const int w = t >> 6;     // 0..15
  const int h = w & 3;      // head
  const int qd = w >> 2;    // j-quarter
  const int m = lane & 15;
  const int q = lane >> 4;
  const int i0 = blockIdx.x * 16;

  const float ssrc = s_src[h * NN + i0 + m];
  const float* stg = s_tgt + h * NN;
  const unsigned* mcol = maskT + i0 + m;
  const short* pb = pTf + (size_t)h * 128 * 2048 + (size_t)lane * 8;

  f32x4 acc0 = {0.f, 0.f, 0.f, 0.f};
  f32x4 acc1 = acc0, acc2 = acc0, acc3 = acc0;
  float lsum = 0.f;

  const int jq = qd * 1024;
  {
    const int jb = jq + q * 8;
    const int tile0 = jq >> 5;
    float4 ct0 = *(const float4*)(stg + jb);
    float4 ct1 = *(const float4*)(stg + jb + 4);
    unsigned cmw = mcol[(size_t)tile0 * NN];
    const short* cp = pb + (size_t)tile0 * 2048;
    bf16x8 cb0 = *(const bf16x8*)(cp);
    bf16x8 cb1 = *(const bf16x8*)(cp + 512);
    bf16x8 cb2 = *(const bf16x8*)(cp + 1024);
    bf16x8 cb3 = *(const bf16x8*)(cp + 1536);

    for (int jt = jq; jt < jq + 1024 - 32; jt += 32) {
      const int ntile = (jt + 32) >> 5;
      const int njb = jt + 32 + q * 8;
      const float4 nt0 = *(const float4*)(stg + njb);
      const float4 nt1 = *(const float4*)(stg + njb + 4);
      const unsigned nmw = mcol[(size_t)ntile * NN];
      const short* np = pb + (size_t)ntile * 2048;
      const bf16x8 nb0 = *(const bf16x8*)(np);
      const bf16x8 nb1 = *(const bf16x8*)(np + 512);
      const bf16x8 nb2 = *(const bf16x8*)(np + 1024);
      const bf16x8 nb3 = *(const bf16x8*)(np + 1536);
      K3_STEP(ct0, ct1, cmw, cb0, cb1, cb2, cb3);
      ct0 = nt0; ct1 = nt1; cmw = nmw;
      cb0 = nb0; cb1 = nb1; cb2 = nb2; cb3 = nb3;
    }
    K3_STEP(ct0, ct1, cmw, cb0, cb1, cb2, cb3);
  }

  // per-wave l partial per row (xor over the 4 q-lanes of each row)
  lsum += __shfl_xor(lsum, 16);
  lsum += __shfl_xor(lsum, 32);
  if (q == 0) lsum_s[w][m] = lsum;

  // per-wave C partials -> LDS (C layout: col = lane&15, row = q*4+g)
  const f32x4 accs[4] = {acc0, acc1, acc2, acc3};
#pragma unroll
  for (int sub = 0; sub < 4; ++sub)
#pragma unroll
    for (int g = 0; g < 4; ++g)
      part[w][q * 4 + g][sub * 16 + m] = accs[sub][g];
  __syncthreads();

  // combine quarters + normalize + skip + elu. 16x256 elements / 1024 threads.
  for (int e = t; e < 16 * 256; e += 1024) {
    const int r = e >> 8;          // row in stripe
    const int c = e & 255;         // output column
    const int hh = c >> 6, cc = c & 63;
    float o = 0.f, l = 0.f;
#pragma unroll
    for (int qq = 0; qq < 4; ++qq) {
      o += part[qq * 4 + hh][r][cc];
      l += lsum_s[qq * 4 + hh][r];
    }
    float z = o / l + io[(size_t)(i0 + r) * DD2 + c];
    z = (z > 0.f) ? z : (__expf(z) - 1.f);   // elu
    io[(size_t)(i0 + r) * DD2 + c] = z;
  }
}

// ---------------------------------------------------------------- k0_w1t
// W1 -> fragment-tiled bf16 w1tf: element W1[j][c] with jt32=j>>5, q=(j>>3)&3,
// e=j&7, n=c>>4, m=c&15 at jt32*3072 + n*512 + (q*16+m)*8 + e, so k56's B-frag
// load (tile, n) = w1tf + tile*3072 + n*512 + lane*8 is a 1KB coalesced
// wave-load. grid 64 (64 j-rows each), block 256; LDS-staged transpose.
// Output into the pT region (dead after k3); launched after k3.
__global__ __launch_bounds__(256) void k0_w1t(
    const float* __restrict__ W1g, short* __restrict__ w1tf)
{
  __shared__ short stw[64 * 97];
  const int t = threadIdx.x;
  const int j0 = blockIdx.x * 64;
  for (int e = t; e < 64 * NH1; e += 256) {
    const int jj = e / NH1, c = e - jj * NH1;
    stw[jj * 97 + c] = f2bf(W1g[(size_t)(j0 + jj) * NH1 + c]);
  }
  __syncthreads();
  for (int o = t; o < 768; o += 256) {   // 768 = 2 tiles x 6 n x 4 q x 16 m
    const int m = o & 15;
    const int rest = o >> 4;             // (tile*6+n)*4+q
    const int q = rest & 3;
    const int tn = rest >> 2;
    const int tile = tn / 6, n = tn - tile * 6;
    bf16x8 v;
#pragma unroll
    for (int e8 = 0; e8 < 8; ++e8)
      v[e8] = stw[(tile * 32 + q * 8 + e8) * 97 + n * 16 + m];
    *(bf16x8*)(w1tf + (size_t)((j0 >> 5) + tile) * 3072 + n * 512
               + (size_t)(q * 16 + m) * 8) = v;
  }
}

// ---------------------------------------------------------------- k4a
// va = Wp2 @ a_src2, vb = Wp2 @ a_tgt2. grid 64, block 256 (wave per row).
__global__ __launch_bounds__(256) void k4a_vab(
    const float* __restrict__ Wp2, const float* __restrict__ as2,
    const float* __restrict__ at2, float* __restrict__ va, float* __restrict__ vb)
{
  const int lane = threadIdx.x & 63;
  const int w = threadIdx.x >> 6;
  const int r = blockIdx.x * 4 + w;
  const float4 wv = *(const float4*)(Wp2 + (size_t)r * DD2 + lane * 4);
  const float4 a = *(const float4*)(as2 + lane * 4);
  const float4 b = *(const float4*)(at2 + lane * 4);
  float ps = wv.x * a.x + wv.y * a.y + wv.z * a.z + wv.w * a.w;
  float pt = wv.x * b.x + wv.y * b.y + wv.z * b.z + wv.w * b.w;
#pragma unroll
  for (int off = 32; off > 0; off >>= 1) {
    ps += __shfl_down(ps, off);
    pt += __shfl_down(pt, off);
  }
  if (lane == 0) { va[r] = ps; vb[r] = pt; }
}

// ---------------------------------------------------------------- k4b
// ss[n] = out_elu[n]·va, st[n] = out_elu[n]·vb. grid 1024, wave per row.
__global__ __launch_bounds__(256) void k4b_sst(
    const float* __restrict__ oe, const float* __restrict__ va,
    const float* __restrict__ vb, float* __restrict__ ss, float* __restrict__ st)
{
  const int lane = threadIdx.x & 63;
  const int w = threadIdx.x >> 6;
  const int r = blockIdx.x * 4 + w;
  const float4 ov = *(const float4*)(oe + (size_t)r * DD2 + lane * 4);
  const float4 a = *(const float4*)(va + lane * 4);
  const float4 b = *(const float4*)(vb + lane * 4);
  float ps = ov.x * a.x + ov.y * a.y + ov.z * a.z + ov.w * a.w;
  float pt = ov.x * b.x + ov.y * b.y + ov.z * b.z + ov.w * b.w;
#pragma unroll
  for (int off = 32; off > 0; off >>= 1) {
    ps += __shfl_down(ps, off);
    pt += __shfl_down(pt, off);
  }
  if (lane == 0) { ss[r] = ps; st[r] = pt; }
}

// ---------------------------------------------------------------- k56
// FUSED k5+k6m: tmp1 = msw @ W1 with msw computed on the fly, M=4096 N=96
// K=4096. grid 2048 = 256 row-stripes x 8 k-splits; block 256 = 4 waves.
// Phase 1: k5's exact coalesced pattern computes v = relu(ss_i+st_j)*sw for
// the block's 16x512 tile -> msw (d_out, fp32) + bf16 A-tile in LDS (cvt_pk).
// Phase 2: k6m's MFMA loop; A-frags = 16B LDS reads, B-frags = w1tf 1KB
// coalesced wave-loads. Phase 3: k6m's LDS reduce + 8-way atomicAdd.
__global__ __launch_bounds__(256) void k56_fused(
    const float* __restrict__ ss, const float* __restrict__ stv,
    const float* __restrict__ sw, const short* __restrict__ w1tf,
    float* __restrict__ msw, float* __restrict__ tmp1)
{
  __shared__ union {
    ushort a[16][520];           // bf16 A-tile (phase 1 -> 2), 16.6 KB
    float red[4][16][NH1];       // cross-wave reduce (phase 3), 24 KB
  } sh;
  const int t = threadIdx.x;
  const int w = t >> 6;
  const int lane = t & 63;
  const int m = lane & 15;
  const int q = lane >> 4;
  const int i0 = (blockIdx.x >> 3) * 16;
  const int j0 = (blockIdx.x & 7) * 512;

  // ---- phase 1: compute + write msw (coalesced) + stash bf16 A-tile
#pragma unroll
  for (int it = 0; it < 8; ++it) {
    const int idx = it * 256 + t;        // float4 slot in 16x512 tile
    const int row = idx >> 7;
    const int colf = idx & 127;
    const int j = j0 + colf * 4;
    const float ssv = ss[i0 + row];
    const float4 wv = *(const float4*)(sw + (size_t)(i0 + row) * NN + j);
    const float4 tv = *(const float4*)(stv + j);
    float4 v;
    v.x = fmaxf(ssv + tv.x, 0.f) * wv.x;
    v.y = fmaxf(ssv + tv.y, 0.f) * wv.y;
    v.z = fmaxf(ssv + tv.z, 0.f) * wv.z;
    v.w = fmaxf(ssv + tv.w, 0.f) * wv.w;
    *(float4*)(msw + (size_t)(i0 + row) * NN + j) = v;
    unsigned p0, p1;
    asm("v_cvt_pk_bf16_f32 %0, %1, %2" : "=v"(p0) : "v"(v.x), "v"(v.y));
    asm("v_cvt_pk_bf16_f32 %0, %1, %2" : "=v"(p1) : "v"(v.z), "v"(v.w));
    uint2 pk; pk.x = p0; pk.y = p1;
    *(uint2*)&sh.a[row][colf * 4] = pk;
  }
  __syncthreads();

  // ---- phase 2: MFMA (k6m structure). wave w covers local j [w*128, +128)
  f32x4 acc[6];
#pragma unroll
  for (int n = 0; n < 6; ++n) acc[n] = {0.f, 0.f, 0.f, 0.f};

#pragma unroll
  for (int kk = 0; kk < 128; kk += 32) {
    const int jloc = w * 128 + kk;
    const bf16x8 af = *(const bf16x8*)&sh.a[m][jloc + q * 8];
    const short* wt = w1tf + (size_t)((j0 + jloc) >> 5) * 3072 + (size_t)lane * 8;
#pragma unroll
    for (int n = 0; n < 6; ++n) {
      const bf16x8 bf = *(const bf16x8*)(wt + n * 512);
      acc[n] = __builtin_amdgcn_mfma_f32_16x16x32_bf16(af, bf, acc[n], 0, 0, 0);
    }
  }
  __syncthreads();   // all A-tile ds_reads done before union reuse

  // ---- phase 3: partials -> LDS (C layout: col = lane&15, row = q*4+g)
#pragma unroll
  for (int n = 0; n < 6; ++n)
#pragma unroll
    for (int g = 0; g < 4; ++g)
      sh.red[w][q * 4 + g][n * 16 + m] = acc[n][g];
  __syncthreads();

  for (int e = t; e < 16 * NH1; e += 256) {
    const int r = e / NH1, c = e - r * NH1;
    const float s = sh.red[0][r][c] + sh.red[1][r][c]
                  + sh.red[2][r][c] + sh.red[3][r][c];
    atomicAdd(&tmp1[(size_t)(i0 + r) * NH1 + c], s);
  }
}

// ---------------------------------------------------------------- k7
// beta/y_hat head. grid 512 (8 rows/block), block 256.
__global__ __launch_bounds__(256) void k7_head(
    const float* __restrict__ tmp1, const float* __restrict__ b1,
    const float* __restrict__ W2, const float* __restrict__ b2,
    const float* __restrict__ W3, const float* __restrict__ b3,
    const float* __restrict__ ols, const float* __restrict__ vx,
    float* __restrict__ beta, float* __restrict__ yhat)
{
  __shared__ float w2s[96][32];
  __shared__ float w3s[32][16];
  __shared__ float t1s[8][96];
  __shared__ float t2s[8][33];
  const int t = threadIdx.x;
  const int r0 = blockIdx.x * 8;
  for (int i = t; i < 96 * 32; i += 256) w2s[i >> 5][i & 31] = W2[i];
  for (int i = t; i < 32 * 16; i += 256) w3s[i >> 4][i & 15] = W3[i];
  for (int i = t; i < 8 * 96; i += 256) {
    const int rr = i / 96, k = i - rr * 96;
    t1s[rr][k] = tmp1[(size_t)(r0 + rr) * 96 + k] + b1[k];
  }
  __syncthreads();
  {
    const int rr = t >> 5, c2 = t & 31;
    float a = b2[c2];
    for (int k = 0; k < 96; ++k) a += t1s[rr][k] * w2s[k][c2];
    t2s[rr][c2] = a;
  }
  __syncthreads();
  const int rr = t >> 5;
  const int v = t & 31;
  if (v < 16) {
    float z = b3[v];
#pragma unroll
    for (int k = 0; k < 32; ++k) z += t2s[rr][k] * w3s[k][v];
    z = fmaxf(z, 0.2f * z);               // leaky_relu(0.2)
    const float bvv = z * ols[v];
    const int r = r0 + rr;
    beta[(size_t)r * 16 + v] = bvv;
    float yv = bvv * vx[(size_t)r * 16 + v];
    yv += __shfl_down(yv, 8);
    yv += __shfl_down(yv, 4);
    yv += __shfl_down(yv, 2);
    yv += __shfl_down(yv, 1);
    if (v == 0) yhat[r] = yv;
  }
}

// ---------------------------------------------------------------- launch
// ws layout (bytes)
#define OFF_PT    0u          // pTf (2MB); w1tf (768KB) reuses this after k3
#define OFF_SKIPB 2097152u
#define OFF_SSRC  6291456u
#define OFF_STGT  6356992u
#define OFF_VA    6422528u
#define OFF_VB    6423552u
#define OFF_SS    6424576u
#define OFF_ST    6440960u
#define OFF_TMP1  6457344u
// d_out layout (floats)
#define OUT_YHAT 65536
#define OUT_MSW  69632

extern "C" void kernel_launch(void* const* d_in, const int* in_sizes, int n_in,
                              void* d_out, int out_size, void* d_ws, size_t ws_size,
                              hipStream_t stream) {
  const float* x    = (const float*)d_in[0];
  // d_in[1] edge_distances: unused by the reference
  const float* sw   = (const float*)d_in[2];
  const float* Wp1  = (const float*)d_in[3];
  const float* as1  = (const float*)d_in[4];
  const float* at1  = (const float*)d_in[5];
  const float* Wsk  = (const float*)d_in[6];
  const float* bias1= (const float*)d_in[7];
  const float* Wp2  = (const float*)d_in[8];
  const float* as2  = (const float*)d_in[9];
  const float* at2  = (const float*)d_in[10];
  const float* W1   = (const float*)d_in[11];
  const float* b1   = (const float*)d_in[12];
  const float* W2   = (const float*)d_in[13];
  const float* b2   = (const float*)d_in[14];
  const float* W3   = (const float*)d_in[15];
  const float* b3   = (const float*)d_in[16];
  const float* ols  = (const float*)d_in[17];
  const float* vx   = (const float*)d_in[18];

  float* out = (float*)d_out;
  char* ws = (char*)d_ws;
  short* pTf   = (short*)(ws + OFF_PT);
  short* w1tf  = (short*)(ws + OFF_PT);      // reuses pTf space (after k3)
  float* skipb = (float*)(ws + OFF_SKIPB);   // becomes out_elu in place (k3)
  float* s_src = (float*)(ws + OFF_SSRC);
  float* s_tgt = (float*)(ws + OFF_STGT);
  float* va    = (float*)(ws + OFF_VA);
  float* vb    = (float*)(ws + OFF_VB);
  float* ssv   = (float*)(ws + OFF_SS);
  float* stv   = (float*)(ws + OFF_ST);
  float* tmp1  = (float*)(ws + OFF_TMP1);
  unsigned* maskT = (unsigned*)(out + OUT_MSW);  // 2MB scratch; k56 overwrites

  k1_proj<<<1024, 256, 0, stream>>>(x, Wp1, Wsk, bias1, as1, at1, pTf, skipb, s_src, s_tgt);
  k2_mask<<<2048, 256, 0, stream>>>(sw, maskT, tmp1);
  k3_attn<<<256, 1024, 0, stream>>>(pTf, s_src, s_tgt, maskT, skipb);
  k0_w1t<<<64, 256, 0, stream>>>(W1, w1tf);  // after k3 (clobbers pTf space)
  k4a_vab<<<64, 256, 0, stream>>>(Wp2, as2, at2, va, vb);
  k4b_sst<<<1024, 256, 0, stream>>>(skipb, va, vb, ssv, stv);
  k56_fused<<<2048, 256, 0, stream>>>(ssv, stv, sw, w1tf, out + OUT_MSW, tmp1);
  k7_head<<<512, 256, 0, stream>>>(tmp1, b1, W2, b2, W3, b3, ols, vx, out, out + OUT_YHAT);
}